// Round 9
// baseline (1193.182 us; speedup 1.0000x reference)
//
#include <hip/hip_runtime.h>
#include <stdint.h>

#define DEV __device__ __forceinline__

constexpr int N0 = 50000;
constexpr int E0 = 800000;
constexpr int D  = 128;

typedef __attribute__((ext_vector_type(8))) short bf16x8;
typedef __attribute__((ext_vector_type(4))) float f32x4;

DEV float bf2f(unsigned u) { return __uint_as_float(u << 16); }
DEV unsigned short f2bf(float f) {
  unsigned u = __float_as_uint(f);
  unsigned r = u + 0x7fffu + ((u >> 16) & 1u);   // round-to-nearest-even
  return (unsigned short)(r >> 16);
}

DEV unsigned wave_incl_scan(unsigned v, int lane) {
  #pragma unroll
  for (int off = 1; off < 64; off <<= 1) {
    unsigned u = __shfl_up(v, (unsigned)off);
    if (lane >= off) v += u;
  }
  return v;
}

DEV unsigned mono_key(float f) {
  unsigned u = __float_as_uint(f);
  return (u & 0x80000000u) ? ~u : (u | 0x80000000u);
}

// ---------------- CSR build ----------------
__global__ void k_count(const int* __restrict__ src, const int* __restrict__ dst,
                        unsigned* cnt_src, unsigned* cnt_dst,
                        unsigned* __restrict__ rank_src, unsigned* __restrict__ rank_dst) {
  int e = blockIdx.x * blockDim.x + threadIdx.x;
  if (e < E0) {
    rank_src[e] = atomicAdd(&cnt_src[src[e]], 1u);
    rank_dst[e] = atomicAdd(&cnt_dst[dst[e]], 1u);
  }
}

// ---- merged 2-array 2-level exclusive scan (y=0: src, y=1: dst) ----
__global__ void k_psum2(const unsigned* __restrict__ in0, const unsigned* __restrict__ in1,
                        int n, unsigned* __restrict__ part) {
  int y = blockIdx.y;
  const unsigned* in = y ? in1 : in0;
  int t = threadIdx.x, lane = t & 63, w = t >> 6;
  int base = blockIdx.x * 1024 + t * 4;
  unsigned s = 0;
  #pragma unroll
  for (int j = 0; j < 4; ++j) { int i = base + j; if (i < n) s += in[i]; }
  #pragma unroll
  for (int off = 32; off >= 1; off >>= 1) s += __shfl_xor(s, off);
  __shared__ unsigned ws[4];
  if (lane == 0) ws[w] = s;
  __syncthreads();
  if (t == 0) part[y * 64 + blockIdx.x] = ws[0] + ws[1] + ws[2] + ws[3];
}

__global__ void k_sapply2(const unsigned* __restrict__ in0, const unsigned* __restrict__ in1,
                          const unsigned* __restrict__ part, int n, int nch,
                          unsigned* __restrict__ out0, unsigned* __restrict__ out1) {
  int y = blockIdx.y;
  const unsigned* in = y ? in1 : in0;
  unsigned* out = y ? out1 : out0;
  int t = threadIdx.x, lane = t & 63, w = t >> 6;
  unsigned c = (lane < (int)blockIdx.x) ? part[y * 64 + lane] : 0u;
  #pragma unroll
  for (int off = 32; off >= 1; off >>= 1) c += __shfl_xor(c, off);
  int base = blockIdx.x * 1024 + t * 4;
  unsigned v[4]; unsigned s = 0;
  #pragma unroll
  for (int j = 0; j < 4; ++j) { int i = base + j; v[j] = (i < n) ? in[i] : 0u; s += v[j]; }
  unsigned incl = wave_incl_scan(s, lane);
  __shared__ unsigned wsum[4], woff[4];
  if (lane == 63) wsum[w] = incl;
  __syncthreads();
  if (t == 0) { unsigned run = 0; for (int j = 0; j < 4; ++j) { woff[j] = run; run += wsum[j]; } }
  __syncthreads();
  unsigned run = c + woff[w] + incl - s;
  #pragma unroll
  for (int j = 0; j < 4; ++j) {
    int i = base + j;
    if (i < n) out[i] = run;
    run += v[j];
  }
  if ((int)blockIdx.x == nch - 1 && t == 0)
    out[n] = c + woff[3] + wsum[3];
}

__global__ void k_fill2(const int* __restrict__ src, const int* __restrict__ dst,
                        const unsigned* __restrict__ rank_src, const unsigned* __restrict__ rank_dst,
                        const unsigned* __restrict__ indptr_src, const unsigned* __restrict__ indptr_dst,
                        int* __restrict__ adj_src, int* __restrict__ adj_dst) {
  int e = blockIdx.x * blockDim.x + threadIdx.x;
  if (e < E0) {
    int s = src[e], d = dst[e];
    adj_dst[indptr_dst[d] + rank_dst[e]] = s;
    adj_src[indptr_src[s] + rank_src[e]] = d;
  }
}

// compose level mask/relabel (both adjacency arrays in one pass)
__global__ void k_adj_next2(const int* __restrict__ adjd, const int* __restrict__ adjs,
                            const int* __restrict__ new_id,
                            int* __restrict__ outd, int* __restrict__ outs) {
  int pos = blockIdx.x * blockDim.x + threadIdx.x;
  if (pos < E0) {
    int a = adjd[pos];
    outd[pos] = (a >= 0) ? new_id[a] : -1;
    int b = adjs[pos];
    outs[pos] = (b >= 0) ? new_id[b] : -1;
  }
}

// ---------------- weight prep: 3-plane split-bf16, MFMA fragment order ----------------
__global__ void k_wt_pk3(const float* __restrict__ Wl, const float* __restrict__ Wr,
                         unsigned short* __restrict__ Bh, unsigned short* __restrict__ Bm,
                         unsigned short* __restrict__ Bl) {
  int idx = blockIdx.x * blockDim.x + threadIdx.x;
  if (idx >= 10 * 8 * 8 * 64) return;
  int l  = idx & 63;
  int ct = (idx >> 6) & 7;
  int ks = (idx >> 9) & 7;
  int c  = idx >> 12;          // conv 0..9
  int k0 = ks * 32 + (l >> 4) * 8;
  int o  = ct * 16 + (l & 15);
  const float* Wrow = (k0 < 128) ? (Wl + ((size_t)c * 128 + o) * 128 + k0)
                                 : (Wr + ((size_t)c * 128 + o) * 128 + (k0 - 128));
  size_t base = (size_t)idx * 8;
  #pragma unroll
  for (int j = 0; j < 8; ++j) {
    float wv = Wrow[j];
    unsigned short h = f2bf(wv);
    float r1 = wv - bf2f(h);
    unsigned short m = f2bf(r1);
    float r2 = r1 - bf2f(m);
    Bh[base + j] = h;
    Bm[base + j] = m;
    Bl[base + j] = f2bf(r2);
  }
}

// ---------------- f32 gather: quarter-wave, 4 rows/step x 4-batch; optional fused score ----------------
template<bool MEAN, bool MASKED, bool ECW, bool SCORE>
__global__ void k_gf32(const float* __restrict__ x, const int* __restrict__ adj,
                       const float* __restrict__ ecs, const unsigned* __restrict__ indptr,
                       const int* __restrict__ orig, int n, float* __restrict__ out,
                       const float* __restrict__ p, float* __restrict__ score,
                       unsigned* __restrict__ keys, unsigned* bins, unsigned* state, int kk) {
  if (SCORE && blockIdx.x == 0) {
    int t = threadIdx.x;
    if (t < 256) bins[t] = 0u;
    if (t == 0) { state[0] = 0u; state[1] = (unsigned)kk; state[2] = 0u; }
  }
  int wid = (blockIdx.x * blockDim.x + threadIdx.x) >> 6;
  int lane = threadIdx.x & 63;
  if (wid >= n) return;
  int o = orig ? orig[wid] : wid;
  unsigned s0 = indptr[o], s1 = indptr[o + 1];
  int q = lane >> 4, sl = lane & 15;
  float acc[8];
  #pragma unroll
  for (int k = 0; k < 8; ++k) acc[k] = 0.f;
  float cnt = 0.f;
  for (unsigned idx = s0; idx < s1; idx += 16) {
    #pragma unroll
    for (int j = 0; j < 4; ++j) {
      unsigned e = idx + j * 4 + q;
      if (e < s1) {
        int a = adj[e];
        if (!MASKED || a >= 0) {
          const float4 v0 = *(const float4*)(x + (size_t)a * D + sl * 8);
          const float4 v1 = *(const float4*)(x + (size_t)a * D + sl * 8 + 4);
          if (ECW) {
            float w = ecs[e];
            acc[0] = fmaf(w, v0.x, acc[0]); acc[1] = fmaf(w, v0.y, acc[1]);
            acc[2] = fmaf(w, v0.z, acc[2]); acc[3] = fmaf(w, v0.w, acc[3]);
            acc[4] = fmaf(w, v1.x, acc[4]); acc[5] = fmaf(w, v1.y, acc[5]);
            acc[6] = fmaf(w, v1.z, acc[6]); acc[7] = fmaf(w, v1.w, acc[7]);
          } else {
            acc[0] += v0.x; acc[1] += v0.y; acc[2] += v0.z; acc[3] += v0.w;
            acc[4] += v1.x; acc[5] += v1.y; acc[6] += v1.z; acc[7] += v1.w;
          }
          cnt += 1.f;
        }
      }
    }
  }
  #pragma unroll
  for (int k = 0; k < 8; ++k) {
    acc[k] += __shfl_xor(acc[k], 16);
    acc[k] += __shfl_xor(acc[k], 32);
  }
  if (MEAN) {
    cnt += __shfl_xor(cnt, 16);
    cnt += __shfl_xor(cnt, 32);
    if (!MASKED) cnt = (float)(s1 - s0);
    float inv = 1.0f / fmaxf(cnt, 1.0f);
    #pragma unroll
    for (int k = 0; k < 8; ++k) acc[k] *= inv;
  }
  if (q == 0) {
    *(float4*)(out + (size_t)wid * D + sl * 8)     = make_float4(acc[0], acc[1], acc[2], acc[3]);
    *(float4*)(out + (size_t)wid * D + sl * 8 + 4) = make_float4(acc[4], acc[5], acc[6], acc[7]);
    if (SCORE) {
      float partial = 0.f, pn = 0.f;
      #pragma unroll
      for (int k = 0; k < 8; ++k) {
        float pv = p[sl * 8 + k];
        partial = fmaf(acc[k], pv, partial);
        pn = fmaf(pv, pv, pn);
      }
      #pragma unroll
      for (int off = 8; off >= 1; off >>= 1) {
        partial += __shfl_xor(partial, off);
        pn += __shfl_xor(pn, off);
      }
      if (sl == 0) {
        float sc = partial * (1.0f / sqrtf(pn));
        score[wid] = sc;
        keys[wid] = mono_key(sc);
      }
    }
  }
}

// ---------------- bf16 gather: quarter-wave, 4 rows/step x 4-batch ----------------
template<bool MEAN, bool MASKED, bool ECW>
__global__ void k_gbf(const unsigned* __restrict__ xb, const int* __restrict__ adj,
                      const float* __restrict__ ecs, const unsigned* __restrict__ indptr,
                      const int* __restrict__ orig, int n,
                      float* __restrict__ out, unsigned* __restrict__ outbf) {
  int wid = (blockIdx.x * blockDim.x + threadIdx.x) >> 6;
  int lane = threadIdx.x & 63;
  if (wid >= n) return;
  int o = orig ? orig[wid] : wid;
  unsigned s0 = indptr[o], s1 = indptr[o + 1];
  int q = lane >> 4, sl = lane & 15;
  float acc[8];
  #pragma unroll
  for (int k = 0; k < 8; ++k) acc[k] = 0.f;
  float cnt = 0.f;
  for (unsigned idx = s0; idx < s1; idx += 16) {
    #pragma unroll
    for (int j = 0; j < 4; ++j) {
      unsigned e = idx + j * 4 + q;
      if (e < s1) {
        int a = adj[e];
        if (!MASKED || a >= 0) {
          const uint4 v = *(const uint4*)(xb + (size_t)a * 64 + sl * 4);
          float f0 = bf2f(v.x & 0xffffu), f1 = bf2f(v.x >> 16);
          float f2 = bf2f(v.y & 0xffffu), f3 = bf2f(v.y >> 16);
          float f4 = bf2f(v.z & 0xffffu), f5 = bf2f(v.z >> 16);
          float f6 = bf2f(v.w & 0xffffu), f7 = bf2f(v.w >> 16);
          if (ECW) {
            float w = ecs[e];
            acc[0] = fmaf(w, f0, acc[0]); acc[1] = fmaf(w, f1, acc[1]);
            acc[2] = fmaf(w, f2, acc[2]); acc[3] = fmaf(w, f3, acc[3]);
            acc[4] = fmaf(w, f4, acc[4]); acc[5] = fmaf(w, f5, acc[5]);
            acc[6] = fmaf(w, f6, acc[6]); acc[7] = fmaf(w, f7, acc[7]);
          } else {
            acc[0] += f0; acc[1] += f1; acc[2] += f2; acc[3] += f3;
            acc[4] += f4; acc[5] += f5; acc[6] += f6; acc[7] += f7;
          }
          cnt += 1.f;
        }
      }
    }
  }
  #pragma unroll
  for (int k = 0; k < 8; ++k) {
    acc[k] += __shfl_xor(acc[k], 16);
    acc[k] += __shfl_xor(acc[k], 32);
  }
  if (MEAN) {
    cnt += __shfl_xor(cnt, 16);
    cnt += __shfl_xor(cnt, 32);
    if (!MASKED) cnt = (float)(s1 - s0);
    float inv = 1.0f / fmaxf(cnt, 1.0f);
    #pragma unroll
    for (int k = 0; k < 8; ++k) acc[k] *= inv;
  }
  if (q == 0) {
    *(float4*)(out + (size_t)wid * D + sl * 8)     = make_float4(acc[0], acc[1], acc[2], acc[3]);
    *(float4*)(out + (size_t)wid * D + sl * 8 + 4) = make_float4(acc[4], acc[5], acc[6], acc[7]);
    if (outbf) {
      uint4 p;
      p.x = (unsigned)f2bf(acc[0]) | ((unsigned)f2bf(acc[1]) << 16);
      p.y = (unsigned)f2bf(acc[2]) | ((unsigned)f2bf(acc[3]) << 16);
      p.z = (unsigned)f2bf(acc[4]) | ((unsigned)f2bf(acc[5]) << 16);
      p.w = (unsigned)f2bf(acc[6]) | ((unsigned)f2bf(acc[7]) << 16);
      *(uint4*)(outbf + (size_t)wid * 64 + sl * 4) = p;
    }
  }
}

// ---------------- 6-term 3-way-split MFMA GEMM (convs 0-3, selection-critical) ----------------
__launch_bounds__(256)
__global__ void k_gemm_mfma6(const float* __restrict__ mean, const float* __restrict__ xin,
                             const unsigned short* __restrict__ Bh, const unsigned short* __restrict__ Bm,
                             const unsigned short* __restrict__ Bl,
                             const float* __restrict__ bias,
                             float* __restrict__ y, int n) {
  int tid = threadIdx.x;
  int lane = tid & 63, w = tid >> 6;
  int row0 = blockIdx.x * 64 + w * 16;
  int arow = row0 + (lane & 15);
  int kgrp = lane >> 4;
  bool rowok = arow < n;
  f32x4 acc[8];
  #pragma unroll
  for (int ct = 0; ct < 8; ++ct) acc[ct] = f32x4{0.f, 0.f, 0.f, 0.f};

  #pragma unroll
  for (int ks = 0; ks < 8; ++ks) {
    const float* A = (ks < 4) ? mean : xin;
    int kk = (ks & 3) * 32 + kgrp * 8;
    float av[8];
    if (rowok) {
      float4 x0 = *(const float4*)(A + (size_t)arow * D + kk);
      float4 x1 = *(const float4*)(A + (size_t)arow * D + kk + 4);
      av[0] = x0.x; av[1] = x0.y; av[2] = x0.z; av[3] = x0.w;
      av[4] = x1.x; av[5] = x1.y; av[6] = x1.z; av[7] = x1.w;
    } else {
      #pragma unroll
      for (int j = 0; j < 8; ++j) av[j] = 0.f;
    }
    bf16x8 ah, am, al;
    #pragma unroll
    for (int j = 0; j < 8; ++j) {
      unsigned short h = f2bf(av[j]);
      float r1 = av[j] - bf2f(h);
      unsigned short m = f2bf(r1);
      float r2 = r1 - bf2f(m);
      ah[j] = (short)h; am[j] = (short)m; al[j] = (short)f2bf(r2);
    }
    #pragma unroll
    for (int ct = 0; ct < 8; ++ct) {
      size_t boff = (((size_t)ks * 8 + ct) * 64 + lane) * 8;
      bf16x8 bh = *(const bf16x8*)(Bh + boff);
      bf16x8 bm = *(const bf16x8*)(Bm + boff);
      bf16x8 bl = *(const bf16x8*)(Bl + boff);
      acc[ct] = __builtin_amdgcn_mfma_f32_16x16x32_bf16(ah, bh, acc[ct], 0, 0, 0);
      acc[ct] = __builtin_amdgcn_mfma_f32_16x16x32_bf16(ah, bm, acc[ct], 0, 0, 0);
      acc[ct] = __builtin_amdgcn_mfma_f32_16x16x32_bf16(am, bh, acc[ct], 0, 0, 0);
      acc[ct] = __builtin_amdgcn_mfma_f32_16x16x32_bf16(am, bm, acc[ct], 0, 0, 0);
      acc[ct] = __builtin_amdgcn_mfma_f32_16x16x32_bf16(ah, bl, acc[ct], 0, 0, 0);
      acc[ct] = __builtin_amdgcn_mfma_f32_16x16x32_bf16(al, bh, acc[ct], 0, 0, 0);
    }
  }
  int ccol = lane & 15;
  #pragma unroll
  for (int ct = 0; ct < 8; ++ct) {
    int col = ct * 16 + ccol;
    float bb = bias[col];
    #pragma unroll
    for (int r = 0; r < 4; ++r) {
      int row = row0 + kgrp * 4 + r;
      if (row < n) y[(size_t)row * D + col] = acc[ct][r] + bb;
    }
  }
}

// ---------------- 3-term split-bf16 MFMA GEMM (convs 4-9, post-selection) ----------------
__launch_bounds__(256)
__global__ void k_gemm_mfma(const float* __restrict__ mean, const float* __restrict__ xin,
                            const unsigned short* __restrict__ Bhi, const unsigned short* __restrict__ Blo,
                            const float* __restrict__ bias, const float* __restrict__ skip,
                            float* __restrict__ y, unsigned short* __restrict__ ybf, int n) {
  int tid = threadIdx.x;
  int lane = tid & 63, w = tid >> 6;
  int row0 = blockIdx.x * 64 + w * 16;
  int arow = row0 + (lane & 15);
  int kgrp = lane >> 4;
  bool rowok = arow < n;
  f32x4 acc[8];
  #pragma unroll
  for (int ct = 0; ct < 8; ++ct) acc[ct] = f32x4{0.f, 0.f, 0.f, 0.f};

  #pragma unroll
  for (int ks = 0; ks < 8; ++ks) {
    const float* A = (ks < 4) ? mean : xin;
    int kk = (ks & 3) * 32 + kgrp * 8;
    float av[8];
    if (rowok) {
      float4 x0 = *(const float4*)(A + (size_t)arow * D + kk);
      float4 x1 = *(const float4*)(A + (size_t)arow * D + kk + 4);
      av[0] = x0.x; av[1] = x0.y; av[2] = x0.z; av[3] = x0.w;
      av[4] = x1.x; av[5] = x1.y; av[6] = x1.z; av[7] = x1.w;
    } else {
      #pragma unroll
      for (int j = 0; j < 8; ++j) av[j] = 0.f;
    }
    bf16x8 ahi, alo;
    #pragma unroll
    for (int j = 0; j < 8; ++j) {
      unsigned short h = f2bf(av[j]);
      ahi[j] = (short)h;
      alo[j] = (short)f2bf(av[j] - bf2f(h));
    }
    #pragma unroll
    for (int ct = 0; ct < 8; ++ct) {
      size_t boff = (((size_t)ks * 8 + ct) * 64 + lane) * 8;
      bf16x8 bh = *(const bf16x8*)(Bhi + boff);
      bf16x8 bl = *(const bf16x8*)(Blo + boff);
      acc[ct] = __builtin_amdgcn_mfma_f32_16x16x32_bf16(ahi, bh, acc[ct], 0, 0, 0);
      acc[ct] = __builtin_amdgcn_mfma_f32_16x16x32_bf16(alo, bh, acc[ct], 0, 0, 0);
      acc[ct] = __builtin_amdgcn_mfma_f32_16x16x32_bf16(ahi, bl, acc[ct], 0, 0, 0);
    }
  }
  int ccol = lane & 15;
  #pragma unroll
  for (int ct = 0; ct < 8; ++ct) {
    int col = ct * 16 + ccol;
    float bb = bias[col];
    #pragma unroll
    for (int r = 0; r < 4; ++r) {
      int row = row0 + kgrp * 4 + r;
      if (row < n) {
        float v = acc[ct][r] + bb;
        if (skip) v += skip[(size_t)row * D + col];
        y[(size_t)row * D + col] = v;
        if (ybf) ybf[(size_t)row * D + col] = f2bf(v);
      }
    }
  }
}

// ---------------- cal_ew ----------------
__global__ void k_deg_mask(const int* __restrict__ adj_src, const unsigned* __restrict__ indptr_src,
                           const int* __restrict__ orig, int n, float* __restrict__ deg) {
  int j = blockIdx.x * blockDim.x + threadIdx.x;
  if (j >= n) return;
  int o = orig ? orig[j] : j;
  unsigned s0 = indptr_src[o], s1 = indptr_src[o + 1];
  float d = 0.f;
  for (unsigned i = s0; i < s1; ++i) d += (adj_src[i] >= 0) ? 1.f : 0.f;
  deg[j] = d;
}

template<bool MASKED>
__global__ void k_ew_dst(const int* __restrict__ adj, const unsigned* __restrict__ indptr,
                         const unsigned* __restrict__ ips,
                         const int* __restrict__ orig, const float* __restrict__ w,
                         const float* __restrict__ deg, int n,
                         float* __restrict__ ws_slot, float* __restrict__ aggrw,
                         float* __restrict__ ec_slot) {
  int j = blockIdx.x * blockDim.x + threadIdx.x;
  if (j >= n) return;
  int o = orig ? orig[j] : j;
  unsigned s0 = indptr[o], s1 = indptr[o + 1];
  float s = 1e-12f;
  for (unsigned pos = s0; pos < s1; ++pos) {
    int a = adj[pos];
    float ws = 0.f;
    if (!MASKED || a >= 0) {
      float d = deg ? deg[a] : (float)(ips[a + 1] - ips[a]);
      ws = (w ? w[a] : 1.0f) / (d > 0.f ? d : 1.0f);
    }
    ws_slot[pos] = ws;
    s += ws;
  }
  aggrw[j] = s;
  float inv = 1.0f / s;
  for (unsigned pos = s0; pos < s1; ++pos) ec_slot[pos] = ws_slot[pos] * inv;
}

template<bool MASKED>
__global__ void k_ew_src(const int* __restrict__ adj_src, const unsigned* __restrict__ indptr_src,
                         const int* __restrict__ orig, const float* __restrict__ w,
                         const float* __restrict__ deg, const float* __restrict__ aggrw, int n,
                         float* __restrict__ ec_slot) {
  int j = blockIdx.x * blockDim.x + threadIdx.x;
  if (j >= n) return;
  int o = orig ? orig[j] : j;
  unsigned s0 = indptr_src[o], s1 = indptr_src[o + 1];
  float d = deg ? deg[j] : (float)(s1 - s0);
  float wn = (w ? w[j] : 1.0f) / (d > 0.f ? d : 1.0f);
  for (unsigned pos = s0; pos < s1; ++pos) {
    int a = adj_src[pos];
    ec_slot[pos] = (!MASKED || a >= 0) ? (wn / aggrw[a]) : 0.f;
  }
}

// ---------------- pooling: fused hist+pick (last-block-done) ----------------
__global__ void k_histpick(const unsigned* __restrict__ keys, int n,
                           unsigned* state, unsigned* bins, int byte) {
  __shared__ unsigned lb[256];
  __shared__ int last;
  for (int i = threadIdx.x; i < 256; i += blockDim.x) lb[i] = 0u;
  __syncthreads();
  unsigned prefix = state[0];
  unsigned mask = (byte == 3) ? 0u : (0xFFFFFFFFu << ((byte + 1) * 8));
  for (int i = blockIdx.x * blockDim.x + threadIdx.x; i < n; i += gridDim.x * blockDim.x) {
    unsigned key = keys[i];
    if ((key & mask) == (prefix & mask))
      atomicAdd(&lb[(key >> (byte * 8)) & 255], 1u);
  }
  __syncthreads();
  for (int i = threadIdx.x; i < 256; i += blockDim.x)
    if (lb[i]) atomicAdd(&bins[i], lb[i]);
  __threadfence();
  if (threadIdx.x == 0) {
    unsigned t = atomicAdd(&state[2], 1u);
    last = (t == gridDim.x - 1) ? 1 : 0;
  }
  __syncthreads();
  if (last) {
    __threadfence();
    if (threadIdx.x == 0) {
      unsigned r = state[1];
      int b;
      for (b = 255; b > 0; --b) {
        unsigned c = bins[b];
        if (c >= r) break;
        r -= c;
      }
      state[0] = prefix | (((unsigned)b) << (byte * 8));
      state[1] = r;
      state[2] = 0u;
    }
    __syncthreads();
    for (int i = threadIdx.x; i < 256; i += blockDim.x) bins[i] = 0u;
  }
}

// ---- parallel pack ----
__global__ void k_flags(const unsigned* __restrict__ keys, const unsigned* __restrict__ state,
                        int n, uint2* __restrict__ part) {
  int t = threadIdx.x, lane = t & 63, w = t >> 6;
  int base = blockIdx.x * 1024 + t * 4;
  unsigned T = state[0];
  unsigned cnt = 0;
  #pragma unroll
  for (int j = 0; j < 4; ++j) {
    int i = base + j;
    if (i < n) {
      unsigned key = keys[i];
      cnt += (key > T ? 1u : 0u) + ((key == T ? 1u : 0u) << 16);
    }
  }
  #pragma unroll
  for (int off = 32; off >= 1; off >>= 1) cnt += __shfl_xor(cnt, off);
  __shared__ unsigned ws[4];
  if (lane == 0) ws[w] = cnt;
  __syncthreads();
  if (t == 0) {
    unsigned s = ws[0] + ws[1] + ws[2] + ws[3];
    part[blockIdx.x] = make_uint2(s & 0xffffu, s >> 16);
  }
}

__global__ void k_pack2(const unsigned* __restrict__ keys, const unsigned* __restrict__ state,
                        const uint2* __restrict__ part, const float* __restrict__ aggrw,
                        const int* __restrict__ orig, int n,
                        int* __restrict__ perm, int* __restrict__ new_id,
                        float* __restrict__ w_next, int* __restrict__ orig_next) {
  int t = threadIdx.x, lane = t & 63, w = t >> 6;
  int base = blockIdx.x * 1024 + t * 4;
  unsigned T = state[0], r = state[1];
  unsigned co = 0;
  if (lane < (int)blockIdx.x) {
    uint2 pp = part[lane];
    co = pp.x | (pp.y << 16);
  }
  #pragma unroll
  for (int off = 32; off >= 1; off >>= 1) co += __shfl_xor(co, off);
  unsigned f[4];
  unsigned cnt = 0;
  #pragma unroll
  for (int j = 0; j < 4; ++j) {
    int i = base + j;
    unsigned key = (i < n) ? keys[i] : 0u;
    unsigned gt = (i < n && key > T) ? 1u : 0u;
    unsigned eq = (i < n && key == T) ? 1u : 0u;
    f[j] = gt | (eq << 1);
    cnt += gt + (eq << 16);
  }
  unsigned incl = wave_incl_scan(cnt, lane);
  __shared__ unsigned wsum[4], woff[4];
  if (lane == 63) wsum[w] = incl;
  __syncthreads();
  if (t == 0) { unsigned run = 0; for (int j = 0; j < 4; ++j) { woff[j] = run; run += wsum[j]; } }
  __syncthreads();
  unsigned before = woff[w] + incl - cnt;
  unsigned gt_b = (co & 0xffffu) + (before & 0xffffu);
  unsigned eq_b = (co >> 16) + (before >> 16);
  #pragma unroll
  for (int j = 0; j < 4; ++j) {
    int i = base + j;
    if (i >= n) break;
    unsigned gt = f[j] & 1u, eq = (f[j] >> 1) & 1u;
    bool sel = gt || (eq && eq_b < r);
    if (sel) {
      int pos = (int)(gt_b + (eq_b < r ? eq_b : r));
      perm[pos] = i;
      new_id[i] = pos;
      w_next[pos] = aggrw[i];
      orig_next[pos] = orig ? orig[i] : i;
    } else {
      new_id[i] = -1;
    }
    gt_b += gt; eq_b += eq;
  }
}

__global__ void k_gate(const float* __restrict__ xin, const int* __restrict__ perm,
                       const float* __restrict__ score, int k, float* __restrict__ xout,
                       unsigned* __restrict__ outbf) {
  int wid = (blockIdx.x * blockDim.x + threadIdx.x) >> 6;
  int lane = threadIdx.x & 63;
  if (wid >= k) return;
  int j = perm[wid];
  float g = tanhf(score[j]);
  float2 v = *(const float2*)(xin + (size_t)j * D + lane * 2);
  v.x *= g; v.y *= g;
  *(float2*)(xout + (size_t)wid * D + lane * 2) = v;
  if (outbf) {
    unsigned p = (unsigned)f2bf(v.x) | ((unsigned)f2bf(v.y) << 16);
    outbf[(size_t)wid * 64 + lane] = p;
  }
}

// =============================================================================
extern "C" void kernel_launch(void* const* d_in, const int* in_sizes, int n_in,
                              void* d_out, int out_size, void* d_ws, size_t ws_size,
                              hipStream_t stream) {
  const float* x_in   = (const float*)d_in[0];
  const int*   ei     = (const int*)d_in[1];
  const int*   src0   = ei;
  const int*   dst0   = ei + E0;
  const float* Wl     = (const float*)d_in[2];
  const float* bl     = (const float*)d_in[3];
  const float* Wr     = (const float*)d_in[4];
  const float* pool_p = (const float*)d_in[5];
  float* out = (float*)d_out;

  const int n0 = N0, k0 = 25000, n1 = 25000, k1 = 12500, n2 = 12500;
  const int NCH0 = (N0 + 1023) / 1024;   // 49

  char* ws = (char*)d_ws;
  size_t off = 0;
  auto alloc = [&](size_t bytes) -> char* {
    char* p = ws + off;
    off += (bytes + 255) & ~(size_t)255;
    return p;
  };
  const size_t NBY = (size_t)N0 * D * 4;
  float* B0    = (float*)alloc(NBY);
  float* B1    = (float*)alloc(NBY);
  float* B2    = (float*)alloc(NBY);
  float* down0 = (float*)alloc(NBY);
  float* down1 = (float*)alloc(NBY / 2);
  unsigned* MA = (unsigned*)alloc((size_t)N0 * D * 2);
  unsigned* MB = (unsigned*)alloc((size_t)N0 * D * 2);
  int* adj0_dst = (int*)alloc(E0 * 4);
  int* adj0_src = (int*)alloc(E0 * 4);
  int* adj1_dst = (int*)alloc(E0 * 4);
  int* adj1_src = (int*)alloc(E0 * 4);
  int* adj2_src = (int*)alloc(E0 * 4);
  float* ec0_src = (float*)alloc(E0 * 4);
  float* ec1_src = (float*)alloc(E0 * 4);
  float* ec_dst  = (float*)alloc(E0 * 4);
  float* ws_slot = (float*)alloc(E0 * 4);
  int* adj2_dst  = (int*)ws_slot;          // alias: ws_slot dead before adj2 is built
  unsigned* rank_src = (unsigned*)alloc(E0 * 4);
  unsigned* rank_dst = (unsigned*)alloc(E0 * 4);
  unsigned* indptr_dst = (unsigned*)alloc((N0 + 1) * 4);
  unsigned* indptr_src = (unsigned*)alloc((N0 + 1) * 4);
  unsigned* cnt_src = (unsigned*)alloc(N0 * 4);
  unsigned* cnt_dst = (unsigned*)alloc(N0 * 4);
  float* deg   = (float*)alloc(N0 * 4);
  float* aggrw = (float*)alloc(N0 * 4);
  float* w1 = (float*)alloc(n1 * 4);
  float* w2 = (float*)alloc(n2 * 4);
  float* score = (float*)alloc(N0 * 4);
  unsigned* keys = (unsigned*)alloc(N0 * 4);
  int* perm0 = (int*)alloc(k0 * 4);
  int* perm1 = (int*)alloc(k1 * 4);
  int* orig1 = (int*)alloc(k0 * 4);
  int* orig2 = (int*)alloc(k1 * 4);
  int* new_id0 = (int*)alloc(N0 * 4);
  int* new_id1 = (int*)alloc(N0 * 4);
  unsigned* bins  = (unsigned*)alloc(256 * 4);
  unsigned* state = (unsigned*)alloc(16);
  unsigned* spart = (unsigned*)alloc(128 * 4);   // [2][64]
  uint2* ppart = (uint2*)alloc(64 * 8);
  unsigned short* Bh = (unsigned short*)alloc((size_t)10 * 32768 * 2);
  unsigned short* Bm = (unsigned short*)alloc((size_t)10 * 32768 * 2);
  unsigned short* Bl = (unsigned short*)alloc((size_t)10 * 32768 * 2);

  const int EG = (E0 + 255) / 256;

  // ---- CSR build ----
  hipMemsetAsync(cnt_src, 0, N0 * 4, stream);
  hipMemsetAsync(cnt_dst, 0, N0 * 4, stream);
  k_count<<<EG, 256, 0, stream>>>(src0, dst0, cnt_src, cnt_dst, rank_src, rank_dst);
  k_psum2<<<dim3(NCH0, 2), 256, 0, stream>>>(cnt_src, cnt_dst, N0, spart);
  k_sapply2<<<dim3(NCH0, 2), 256, 0, stream>>>(cnt_src, cnt_dst, spart, N0, NCH0,
                                               indptr_src, indptr_dst);
  k_fill2<<<EG, 256, 0, stream>>>(src0, dst0, rank_src, rank_dst, indptr_src, indptr_dst,
                                  adj0_src, adj0_dst);
  k_wt_pk3<<<(10 * 8 * 8 * 64 + 255) / 256, 256, 0, stream>>>(Wl, Wr, Bh, Bm, Bl);

  auto gemm6 = [&](const float* meanb, const float* xin, float* yout, int n, int cidx) {
    size_t o = (size_t)cidx * 32768;
    k_gemm_mfma6<<<(n + 63) / 64, 256, 0, stream>>>(meanb, xin, Bh + o, Bm + o, Bl + o,
                                                    bl + cidx * 128, yout, n);
  };
  auto gemm_mx = [&](const float* meanb, const float* xin, float* yout, unsigned short* ybf,
                     const float* skip, int n, int cidx) {
    size_t o = (size_t)cidx * 32768;
    k_gemm_mfma<<<(n + 63) / 64, 256, 0, stream>>>(meanb, xin, Bh + o, Bm + o,
                                                   bl + cidx * 128, skip, yout, ybf, n);
  };

  // pool (score/keys already produced by the fused econv): 4x histpick, flags, pack, gate
  auto pool_sel = [&](const float* xpool, int n, int kk, const int* orig,
                      int* perm, int* nid, float* w_next, int* orig_next,
                      float* xout, unsigned* xout_bf) {
    int nch = (n + 1023) / 1024;
    for (int byte = 3; byte >= 0; --byte)
      k_histpick<<<256, 256, 0, stream>>>(keys, n, state, bins, byte);
    k_flags<<<nch, 256, 0, stream>>>(keys, state, n, ppart);
    k_pack2<<<nch, 256, 0, stream>>>(keys, state, ppart, aggrw, orig, n, perm, nid, w_next, orig_next);
    k_gate<<<((kk + 3) / 4), 256, 0, stream>>>(xpool, perm, score, kk, xout, xout_bf);
  };

  const int G0 = (n0 + 3) / 4, G1 = (n1 + 3) / 4, G2 = (n2 + 3) / 4;

  // ======== down level 0 (f32, selection-exact) ========
  k_gf32<true, false, false, false><<<G0, 256, 0, stream>>>(x_in, adj0_dst, nullptr, indptr_dst,
      nullptr, n0, B1, nullptr, nullptr, nullptr, nullptr, nullptr, 0);
  gemm6(B1, x_in, B2, n0, 0);
  k_gf32<true, false, false, false><<<G0, 256, 0, stream>>>(B2, adj0_dst, nullptr, indptr_dst,
      nullptr, n0, B1, nullptr, nullptr, nullptr, nullptr, nullptr, 0);
  gemm6(B1, B2, down0, n0, 1);
  k_ew_dst<false><<<(n0 + 255) / 256, 256, 0, stream>>>(adj0_dst, indptr_dst, indptr_src, nullptr,
                                                        nullptr, nullptr, n0, ws_slot, aggrw, ec_dst);
  k_ew_src<false><<<(n0 + 255) / 256, 256, 0, stream>>>(adj0_src, indptr_src, nullptr, nullptr,
                                                        nullptr, aggrw, n0, ec0_src);
  // econv + fused score/keys + select-state init
  k_gf32<false, false, true, true><<<G0, 256, 0, stream>>>(down0, adj0_dst, ec_dst, indptr_dst,
      nullptr, n0, B1, pool_p, score, keys, bins, state, k0);
  pool_sel(B1, n0, k0, nullptr, perm0, new_id0, w1, orig1, B2, nullptr);
  k_adj_next2<<<EG, 256, 0, stream>>>(adj0_dst, adj0_src, new_id0, adj1_dst, adj1_src);

  // ======== down level 1 (f32) ========
  k_gf32<true, true, false, false><<<G1, 256, 0, stream>>>(B2, adj1_dst, nullptr, indptr_dst,
      orig1, n1, B1, nullptr, nullptr, nullptr, nullptr, nullptr, 0);
  gemm6(B1, B2, B0, n1, 2);
  k_gf32<true, true, false, false><<<G1, 256, 0, stream>>>(B0, adj1_dst, nullptr, indptr_dst,
      orig1, n1, B1, nullptr, nullptr, nullptr, nullptr, nullptr, 0);
  gemm6(B1, B0, down1, n1, 3);
  k_deg_mask<<<(n1 + 255) / 256, 256, 0, stream>>>(adj1_src, indptr_src, orig1, n1, deg);
  k_ew_dst<true><<<(n1 + 255) / 256, 256, 0, stream>>>(adj1_dst, indptr_dst, nullptr, orig1, w1,
                                                       deg, n1, ws_slot, aggrw, ec_dst);
  k_ew_src<true><<<(n1 + 255) / 256, 256, 0, stream>>>(adj1_src, indptr_src, orig1, w1, deg, aggrw,
                                                       n1, ec1_src);
  k_gf32<false, true, true, true><<<G1, 256, 0, stream>>>(down1, adj1_dst, ec_dst, indptr_dst,
      orig1, n1, B1, pool_p + D, score, keys, bins, state, k1);
  pool_sel(B1, n1, k1, orig1, perm1, new_id1, w2, orig2, B2, MA);
  k_adj_next2<<<EG, 256, 0, stream>>>(adj1_dst, adj1_src, new_id1, adj2_dst, adj2_src);

  // ======== bottom (bf16 gathers, MFMA convs) ========
  k_gbf<true, true, false><<<G2, 256, 0, stream>>>(MA, adj2_dst, nullptr, indptr_dst, orig2, n2, B1, nullptr);
  gemm_mx(B1, B2, B0, (unsigned short*)MB, nullptr, n2, 4);
  k_gbf<true, true, false><<<G2, 256, 0, stream>>>(MB, adj2_dst, nullptr, indptr_dst, orig2, n2, B1, nullptr);
  gemm_mx(B1, B0, B2, (unsigned short*)MA, nullptr, n2, 5);   // emit compact n2 mirror for up1

  // ======== up u=1 (direct-compact econv via adj2_src; skip fused into conv 7) ========
  k_gbf<false, true, true><<<G1, 256, 0, stream>>>(MA, adj2_src, ec1_src, indptr_src, orig1, n1, B1, MB);
  k_gbf<true, true, false><<<G1, 256, 0, stream>>>(MB, adj1_dst, nullptr, indptr_dst, orig1, n1, B0, nullptr);
  gemm_mx(B0, B1, B2, (unsigned short*)MA, nullptr, n1, 6);
  k_gbf<true, true, false><<<G1, 256, 0, stream>>>(MA, adj1_dst, nullptr, indptr_dst, orig1, n1, B0, nullptr);
  gemm_mx(B0, B2, B1, (unsigned short*)MA, down1, n1, 7);     // emit compact n1 mirror for up0

  // ======== up u=0 (direct-compact econv via adj1_src; skip fused into conv 9) ========
  k_gbf<false, true, true><<<G0, 256, 0, stream>>>(MA, adj1_src, ec0_src, indptr_src, nullptr, n0, B2, MB);
  k_gbf<true, false, false><<<G0, 256, 0, stream>>>(MB, adj0_dst, nullptr, indptr_dst, nullptr, n0, B1, nullptr);
  gemm_mx(B1, B2, B0, (unsigned short*)MA, nullptr, n0, 8);
  k_gbf<true, false, false><<<G0, 256, 0, stream>>>(MA, adj0_dst, nullptr, indptr_dst, nullptr, n0, B1, nullptr);
  gemm_mx(B1, B0, out, nullptr, down0, n0, 9);
}

// Round 10
// 1078.733 us; speedup vs baseline: 1.1061x; 1.1061x over previous
//
#include <hip/hip_runtime.h>
#include <stdint.h>

#define DEV __device__ __forceinline__

constexpr int N0 = 50000;
constexpr int E0 = 800000;
constexpr int D  = 128;

typedef __attribute__((ext_vector_type(8))) short bf16x8;
typedef __attribute__((ext_vector_type(4))) float f32x4;

DEV float bf2f(unsigned u) { return __uint_as_float(u << 16); }
DEV unsigned short f2bf(float f) {
  unsigned u = __float_as_uint(f);
  unsigned r = u + 0x7fffu + ((u >> 16) & 1u);   // round-to-nearest-even
  return (unsigned short)(r >> 16);
}

DEV unsigned wave_incl_scan(unsigned v, int lane) {
  #pragma unroll
  for (int off = 1; off < 64; off <<= 1) {
    unsigned u = __shfl_up(v, (unsigned)off);
    if (lane >= off) v += u;
  }
  return v;
}

DEV unsigned mono_key(float f) {
  unsigned u = __float_as_uint(f);
  return (u & 0x80000000u) ? ~u : (u | 0x80000000u);
}

// ---------------- CSR build ----------------
__global__ void k_count(const int* __restrict__ src, const int* __restrict__ dst,
                        unsigned* cnt_src, unsigned* cnt_dst,
                        unsigned* __restrict__ rank_src, unsigned* __restrict__ rank_dst) {
  int e = blockIdx.x * blockDim.x + threadIdx.x;
  if (e < E0) {
    rank_src[e] = atomicAdd(&cnt_src[src[e]], 1u);
    rank_dst[e] = atomicAdd(&cnt_dst[dst[e]], 1u);
  }
}

// ---- merged 2-array 2-level exclusive scan (y=0: src, y=1: dst) ----
__global__ void k_psum2(const unsigned* __restrict__ in0, const unsigned* __restrict__ in1,
                        int n, unsigned* __restrict__ part) {
  int y = blockIdx.y;
  const unsigned* in = y ? in1 : in0;
  int t = threadIdx.x, lane = t & 63, w = t >> 6;
  int base = blockIdx.x * 1024 + t * 4;
  unsigned s = 0;
  #pragma unroll
  for (int j = 0; j < 4; ++j) { int i = base + j; if (i < n) s += in[i]; }
  #pragma unroll
  for (int off = 32; off >= 1; off >>= 1) s += __shfl_xor(s, off);
  __shared__ unsigned ws[4];
  if (lane == 0) ws[w] = s;
  __syncthreads();
  if (t == 0) part[y * 64 + blockIdx.x] = ws[0] + ws[1] + ws[2] + ws[3];
}

__global__ void k_sapply2(const unsigned* __restrict__ in0, const unsigned* __restrict__ in1,
                          const unsigned* __restrict__ part, int n, int nch,
                          unsigned* __restrict__ out0, unsigned* __restrict__ out1) {
  int y = blockIdx.y;
  const unsigned* in = y ? in1 : in0;
  unsigned* out = y ? out1 : out0;
  int t = threadIdx.x, lane = t & 63, w = t >> 6;
  unsigned c = (lane < (int)blockIdx.x) ? part[y * 64 + lane] : 0u;
  #pragma unroll
  for (int off = 32; off >= 1; off >>= 1) c += __shfl_xor(c, off);
  int base = blockIdx.x * 1024 + t * 4;
  unsigned v[4]; unsigned s = 0;
  #pragma unroll
  for (int j = 0; j < 4; ++j) { int i = base + j; v[j] = (i < n) ? in[i] : 0u; s += v[j]; }
  unsigned incl = wave_incl_scan(s, lane);
  __shared__ unsigned wsum[4], woff[4];
  if (lane == 63) wsum[w] = incl;
  __syncthreads();
  if (t == 0) { unsigned run = 0; for (int j = 0; j < 4; ++j) { woff[j] = run; run += wsum[j]; } }
  __syncthreads();
  unsigned run = c + woff[w] + incl - s;
  #pragma unroll
  for (int j = 0; j < 4; ++j) {
    int i = base + j;
    if (i < n) out[i] = run;
    run += v[j];
  }
  if ((int)blockIdx.x == nch - 1 && t == 0)
    out[n] = c + woff[3] + wsum[3];
}

__global__ void k_fill2(const int* __restrict__ src, const int* __restrict__ dst,
                        const unsigned* __restrict__ rank_src, const unsigned* __restrict__ rank_dst,
                        const unsigned* __restrict__ indptr_src, const unsigned* __restrict__ indptr_dst,
                        int* __restrict__ adj_src, int* __restrict__ adj_dst) {
  int e = blockIdx.x * blockDim.x + threadIdx.x;
  if (e < E0) {
    int s = src[e], d = dst[e];
    adj_dst[indptr_dst[d] + rank_dst[e]] = s;
    adj_src[indptr_src[s] + rank_src[e]] = d;
  }
}

__global__ void k_adj_next2(const int* __restrict__ adjd, const int* __restrict__ adjs,
                            const int* __restrict__ new_id,
                            int* __restrict__ outd, int* __restrict__ outs) {
  int pos = blockIdx.x * blockDim.x + threadIdx.x;
  if (pos < E0) {
    int a = adjd[pos];
    outd[pos] = (a >= 0) ? new_id[a] : -1;
    int b = adjs[pos];
    outs[pos] = (b >= 0) ? new_id[b] : -1;
  }
}

__global__ void k_adj_next(const int* __restrict__ adj_prev, const int* __restrict__ new_id,
                           int* __restrict__ adj_out) {
  int pos = blockIdx.x * blockDim.x + threadIdx.x;
  if (pos < E0) {
    int a = adj_prev[pos];
    adj_out[pos] = (a >= 0) ? new_id[a] : -1;
  }
}

// ---------------- weight prep: 3-plane split-bf16, MFMA fragment order ----------------
__global__ void k_wt_pk3(const float* __restrict__ Wl, const float* __restrict__ Wr,
                         unsigned short* __restrict__ Bh, unsigned short* __restrict__ Bm,
                         unsigned short* __restrict__ Bl) {
  int idx = blockIdx.x * blockDim.x + threadIdx.x;
  if (idx >= 10 * 8 * 8 * 64) return;
  int l  = idx & 63;
  int ct = (idx >> 6) & 7;
  int ks = (idx >> 9) & 7;
  int c  = idx >> 12;          // conv 0..9
  int k0 = ks * 32 + (l >> 4) * 8;
  int o  = ct * 16 + (l & 15);
  const float* Wrow = (k0 < 128) ? (Wl + ((size_t)c * 128 + o) * 128 + k0)
                                 : (Wr + ((size_t)c * 128 + o) * 128 + (k0 - 128));
  size_t base = (size_t)idx * 8;
  #pragma unroll
  for (int j = 0; j < 8; ++j) {
    float wv = Wrow[j];
    unsigned short h = f2bf(wv);
    float r1 = wv - bf2f(h);
    unsigned short m = f2bf(r1);
    float r2 = r1 - bf2f(m);
    Bh[base + j] = h;
    Bm[base + j] = m;
    Bl[base + j] = f2bf(r2);
  }
}

// ---------------- f32 gather: quarter-wave, 4 rows/step x 4-batch; optional fused score ----------------
template<bool MEAN, bool MASKED, bool ECW, bool SCORE>
__global__ void k_gf32(const float* __restrict__ x, const int* __restrict__ adj,
                       const float* __restrict__ ecs, const unsigned* __restrict__ indptr,
                       const int* __restrict__ orig, int n, float* __restrict__ out,
                       const float* __restrict__ p, float* __restrict__ score,
                       unsigned* __restrict__ keys, unsigned* bins, unsigned* state, int kk) {
  if (SCORE && blockIdx.x == 0) {
    int t = threadIdx.x;
    if (t < 256) bins[t] = 0u;
    if (t == 0) { state[0] = 0u; state[1] = (unsigned)kk; }
  }
  int wid = (blockIdx.x * blockDim.x + threadIdx.x) >> 6;
  int lane = threadIdx.x & 63;
  if (wid >= n) return;
  int o = orig ? orig[wid] : wid;
  unsigned s0 = indptr[o], s1 = indptr[o + 1];
  int q = lane >> 4, sl = lane & 15;
  float acc[8];
  #pragma unroll
  for (int k = 0; k < 8; ++k) acc[k] = 0.f;
  float cnt = 0.f;
  for (unsigned idx = s0; idx < s1; idx += 16) {
    #pragma unroll
    for (int j = 0; j < 4; ++j) {
      unsigned e = idx + j * 4 + q;
      if (e < s1) {
        int a = adj[e];
        if (!MASKED || a >= 0) {
          const float4 v0 = *(const float4*)(x + (size_t)a * D + sl * 8);
          const float4 v1 = *(const float4*)(x + (size_t)a * D + sl * 8 + 4);
          if (ECW) {
            float w = ecs[e];
            acc[0] = fmaf(w, v0.x, acc[0]); acc[1] = fmaf(w, v0.y, acc[1]);
            acc[2] = fmaf(w, v0.z, acc[2]); acc[3] = fmaf(w, v0.w, acc[3]);
            acc[4] = fmaf(w, v1.x, acc[4]); acc[5] = fmaf(w, v1.y, acc[5]);
            acc[6] = fmaf(w, v1.z, acc[6]); acc[7] = fmaf(w, v1.w, acc[7]);
          } else {
            acc[0] += v0.x; acc[1] += v0.y; acc[2] += v0.z; acc[3] += v0.w;
            acc[4] += v1.x; acc[5] += v1.y; acc[6] += v1.z; acc[7] += v1.w;
          }
          cnt += 1.f;
        }
      }
    }
  }
  #pragma unroll
  for (int k = 0; k < 8; ++k) {
    acc[k] += __shfl_xor(acc[k], 16);
    acc[k] += __shfl_xor(acc[k], 32);
  }
  if (MEAN) {
    cnt += __shfl_xor(cnt, 16);
    cnt += __shfl_xor(cnt, 32);
    if (!MASKED) cnt = (float)(s1 - s0);
    float inv = 1.0f / fmaxf(cnt, 1.0f);
    #pragma unroll
    for (int k = 0; k < 8; ++k) acc[k] *= inv;
  }
  if (q == 0) {
    *(float4*)(out + (size_t)wid * D + sl * 8)     = make_float4(acc[0], acc[1], acc[2], acc[3]);
    *(float4*)(out + (size_t)wid * D + sl * 8 + 4) = make_float4(acc[4], acc[5], acc[6], acc[7]);
    if (SCORE) {
      float partial = 0.f, pn = 0.f;
      #pragma unroll
      for (int k = 0; k < 8; ++k) {
        float pv = p[sl * 8 + k];
        partial = fmaf(acc[k], pv, partial);
        pn = fmaf(pv, pv, pn);
      }
      #pragma unroll
      for (int off = 8; off >= 1; off >>= 1) {
        partial += __shfl_xor(partial, off);
        pn += __shfl_xor(pn, off);
      }
      if (sl == 0) {
        float sc = partial * (1.0f / sqrtf(pn));
        score[wid] = sc;
        keys[wid] = mono_key(sc);
      }
    }
  }
}

// ---------------- bf16 gather: quarter-wave, 4 rows/step x 4-batch ----------------
template<bool MEAN, bool MASKED, bool ECW>
__global__ void k_gbf(const unsigned* __restrict__ xb, const int* __restrict__ adj,
                      const float* __restrict__ ecs, const unsigned* __restrict__ indptr,
                      const int* __restrict__ orig, int n,
                      float* __restrict__ out, unsigned* __restrict__ outbf) {
  int wid = (blockIdx.x * blockDim.x + threadIdx.x) >> 6;
  int lane = threadIdx.x & 63;
  if (wid >= n) return;
  int o = orig ? orig[wid] : wid;
  unsigned s0 = indptr[o], s1 = indptr[o + 1];
  int q = lane >> 4, sl = lane & 15;
  float acc[8];
  #pragma unroll
  for (int k = 0; k < 8; ++k) acc[k] = 0.f;
  float cnt = 0.f;
  for (unsigned idx = s0; idx < s1; idx += 16) {
    #pragma unroll
    for (int j = 0; j < 4; ++j) {
      unsigned e = idx + j * 4 + q;
      if (e < s1) {
        int a = adj[e];
        if (!MASKED || a >= 0) {
          const uint4 v = *(const uint4*)(xb + (size_t)a * 64 + sl * 4);
          float f0 = bf2f(v.x & 0xffffu), f1 = bf2f(v.x >> 16);
          float f2 = bf2f(v.y & 0xffffu), f3 = bf2f(v.y >> 16);
          float f4 = bf2f(v.z & 0xffffu), f5 = bf2f(v.z >> 16);
          float f6 = bf2f(v.w & 0xffffu), f7 = bf2f(v.w >> 16);
          if (ECW) {
            float w = ecs[e];
            acc[0] = fmaf(w, f0, acc[0]); acc[1] = fmaf(w, f1, acc[1]);
            acc[2] = fmaf(w, f2, acc[2]); acc[3] = fmaf(w, f3, acc[3]);
            acc[4] = fmaf(w, f4, acc[4]); acc[5] = fmaf(w, f5, acc[5]);
            acc[6] = fmaf(w, f6, acc[6]); acc[7] = fmaf(w, f7, acc[7]);
          } else {
            acc[0] += f0; acc[1] += f1; acc[2] += f2; acc[3] += f3;
            acc[4] += f4; acc[5] += f5; acc[6] += f6; acc[7] += f7;
          }
          cnt += 1.f;
        }
      }
    }
  }
  #pragma unroll
  for (int k = 0; k < 8; ++k) {
    acc[k] += __shfl_xor(acc[k], 16);
    acc[k] += __shfl_xor(acc[k], 32);
  }
  if (MEAN) {
    cnt += __shfl_xor(cnt, 16);
    cnt += __shfl_xor(cnt, 32);
    if (!MASKED) cnt = (float)(s1 - s0);
    float inv = 1.0f / fmaxf(cnt, 1.0f);
    #pragma unroll
    for (int k = 0; k < 8; ++k) acc[k] *= inv;
  }
  if (q == 0) {
    *(float4*)(out + (size_t)wid * D + sl * 8)     = make_float4(acc[0], acc[1], acc[2], acc[3]);
    *(float4*)(out + (size_t)wid * D + sl * 8 + 4) = make_float4(acc[4], acc[5], acc[6], acc[7]);
    if (outbf) {
      uint4 p;
      p.x = (unsigned)f2bf(acc[0]) | ((unsigned)f2bf(acc[1]) << 16);
      p.y = (unsigned)f2bf(acc[2]) | ((unsigned)f2bf(acc[3]) << 16);
      p.z = (unsigned)f2bf(acc[4]) | ((unsigned)f2bf(acc[5]) << 16);
      p.w = (unsigned)f2bf(acc[6]) | ((unsigned)f2bf(acc[7]) << 16);
      *(uint4*)(outbf + (size_t)wid * 64 + sl * 4) = p;
    }
  }
}

// ---------------- 6-term 3-way-split MFMA GEMM (convs 0-3, selection-critical) ----------------
__launch_bounds__(256)
__global__ void k_gemm_mfma6(const float* __restrict__ mean, const float* __restrict__ xin,
                             const unsigned short* __restrict__ Bh, const unsigned short* __restrict__ Bm,
                             const unsigned short* __restrict__ Bl,
                             const float* __restrict__ bias,
                             float* __restrict__ y, int n) {
  int tid = threadIdx.x;
  int lane = tid & 63, w = tid >> 6;
  int row0 = blockIdx.x * 64 + w * 16;
  int arow = row0 + (lane & 15);
  int kgrp = lane >> 4;
  bool rowok = arow < n;
  f32x4 acc[8];
  #pragma unroll
  for (int ct = 0; ct < 8; ++ct) acc[ct] = f32x4{0.f, 0.f, 0.f, 0.f};

  #pragma unroll
  for (int ks = 0; ks < 8; ++ks) {
    const float* A = (ks < 4) ? mean : xin;
    int kk = (ks & 3) * 32 + kgrp * 8;
    float av[8];
    if (rowok) {
      float4 x0 = *(const float4*)(A + (size_t)arow * D + kk);
      float4 x1 = *(const float4*)(A + (size_t)arow * D + kk + 4);
      av[0] = x0.x; av[1] = x0.y; av[2] = x0.z; av[3] = x0.w;
      av[4] = x1.x; av[5] = x1.y; av[6] = x1.z; av[7] = x1.w;
    } else {
      #pragma unroll
      for (int j = 0; j < 8; ++j) av[j] = 0.f;
    }
    bf16x8 ah, am, al;
    #pragma unroll
    for (int j = 0; j < 8; ++j) {
      unsigned short h = f2bf(av[j]);
      float r1 = av[j] - bf2f(h);
      unsigned short m = f2bf(r1);
      float r2 = r1 - bf2f(m);
      ah[j] = (short)h; am[j] = (short)m; al[j] = (short)f2bf(r2);
    }
    #pragma unroll
    for (int ct = 0; ct < 8; ++ct) {
      size_t boff = (((size_t)ks * 8 + ct) * 64 + lane) * 8;
      bf16x8 bh = *(const bf16x8*)(Bh + boff);
      bf16x8 bm = *(const bf16x8*)(Bm + boff);
      bf16x8 bl = *(const bf16x8*)(Bl + boff);
      acc[ct] = __builtin_amdgcn_mfma_f32_16x16x32_bf16(ah, bh, acc[ct], 0, 0, 0);
      acc[ct] = __builtin_amdgcn_mfma_f32_16x16x32_bf16(ah, bm, acc[ct], 0, 0, 0);
      acc[ct] = __builtin_amdgcn_mfma_f32_16x16x32_bf16(am, bh, acc[ct], 0, 0, 0);
      acc[ct] = __builtin_amdgcn_mfma_f32_16x16x32_bf16(am, bm, acc[ct], 0, 0, 0);
      acc[ct] = __builtin_amdgcn_mfma_f32_16x16x32_bf16(ah, bl, acc[ct], 0, 0, 0);
      acc[ct] = __builtin_amdgcn_mfma_f32_16x16x32_bf16(al, bh, acc[ct], 0, 0, 0);
    }
  }
  int ccol = lane & 15;
  #pragma unroll
  for (int ct = 0; ct < 8; ++ct) {
    int col = ct * 16 + ccol;
    float bb = bias[col];
    #pragma unroll
    for (int r = 0; r < 4; ++r) {
      int row = row0 + kgrp * 4 + r;
      if (row < n) y[(size_t)row * D + col] = acc[ct][r] + bb;
    }
  }
}

// ---------------- 3-term split-bf16 MFMA GEMM (convs 4-9, post-selection) ----------------
__launch_bounds__(256)
__global__ void k_gemm_mfma(const float* __restrict__ mean, const float* __restrict__ xin,
                            const unsigned short* __restrict__ Bhi, const unsigned short* __restrict__ Blo,
                            const float* __restrict__ bias, const float* __restrict__ skip,
                            float* __restrict__ y, unsigned short* __restrict__ ybf, int n) {
  int tid = threadIdx.x;
  int lane = tid & 63, w = tid >> 6;
  int row0 = blockIdx.x * 64 + w * 16;
  int arow = row0 + (lane & 15);
  int kgrp = lane >> 4;
  bool rowok = arow < n;
  f32x4 acc[8];
  #pragma unroll
  for (int ct = 0; ct < 8; ++ct) acc[ct] = f32x4{0.f, 0.f, 0.f, 0.f};

  #pragma unroll
  for (int ks = 0; ks < 8; ++ks) {
    const float* A = (ks < 4) ? mean : xin;
    int kk = (ks & 3) * 32 + kgrp * 8;
    float av[8];
    if (rowok) {
      float4 x0 = *(const float4*)(A + (size_t)arow * D + kk);
      float4 x1 = *(const float4*)(A + (size_t)arow * D + kk + 4);
      av[0] = x0.x; av[1] = x0.y; av[2] = x0.z; av[3] = x0.w;
      av[4] = x1.x; av[5] = x1.y; av[6] = x1.z; av[7] = x1.w;
    } else {
      #pragma unroll
      for (int j = 0; j < 8; ++j) av[j] = 0.f;
    }
    bf16x8 ahi, alo;
    #pragma unroll
    for (int j = 0; j < 8; ++j) {
      unsigned short h = f2bf(av[j]);
      ahi[j] = (short)h;
      alo[j] = (short)f2bf(av[j] - bf2f(h));
    }
    #pragma unroll
    for (int ct = 0; ct < 8; ++ct) {
      size_t boff = (((size_t)ks * 8 + ct) * 64 + lane) * 8;
      bf16x8 bh = *(const bf16x8*)(Bhi + boff);
      bf16x8 bl = *(const bf16x8*)(Blo + boff);
      acc[ct] = __builtin_amdgcn_mfma_f32_16x16x32_bf16(ahi, bh, acc[ct], 0, 0, 0);
      acc[ct] = __builtin_amdgcn_mfma_f32_16x16x32_bf16(alo, bh, acc[ct], 0, 0, 0);
      acc[ct] = __builtin_amdgcn_mfma_f32_16x16x32_bf16(ahi, bl, acc[ct], 0, 0, 0);
    }
  }
  int ccol = lane & 15;
  #pragma unroll
  for (int ct = 0; ct < 8; ++ct) {
    int col = ct * 16 + ccol;
    float bb = bias[col];
    #pragma unroll
    for (int r = 0; r < 4; ++r) {
      int row = row0 + kgrp * 4 + r;
      if (row < n) {
        float v = acc[ct][r] + bb;
        if (skip) v += skip[(size_t)row * D + col];
        y[(size_t)row * D + col] = v;
        if (ybf) ybf[(size_t)row * D + col] = f2bf(v);
      }
    }
  }
}

// ---------------- cal_ew ----------------
__global__ void k_deg_mask(const int* __restrict__ adj_src, const unsigned* __restrict__ indptr_src,
                           const int* __restrict__ orig, int n, float* __restrict__ deg) {
  int j = blockIdx.x * blockDim.x + threadIdx.x;
  if (j >= n) return;
  int o = orig ? orig[j] : j;
  unsigned s0 = indptr_src[o], s1 = indptr_src[o + 1];
  float d = 0.f;
  for (unsigned i = s0; i < s1; ++i) d += (adj_src[i] >= 0) ? 1.f : 0.f;
  deg[j] = d;
}

template<bool MASKED>
__global__ void k_ew_dst(const int* __restrict__ adj, const unsigned* __restrict__ indptr,
                         const unsigned* __restrict__ ips,
                         const int* __restrict__ orig, const float* __restrict__ w,
                         const float* __restrict__ deg, int n,
                         float* __restrict__ ws_slot, float* __restrict__ aggrw,
                         float* __restrict__ ec_slot) {
  int j = blockIdx.x * blockDim.x + threadIdx.x;
  if (j >= n) return;
  int o = orig ? orig[j] : j;
  unsigned s0 = indptr[o], s1 = indptr[o + 1];
  float s = 1e-12f;
  for (unsigned pos = s0; pos < s1; ++pos) {
    int a = adj[pos];
    float ws = 0.f;
    if (!MASKED || a >= 0) {
      float d = deg ? deg[a] : (float)(ips[a + 1] - ips[a]);
      ws = (w ? w[a] : 1.0f) / (d > 0.f ? d : 1.0f);
    }
    ws_slot[pos] = ws;
    s += ws;
  }
  aggrw[j] = s;
  float inv = 1.0f / s;
  for (unsigned pos = s0; pos < s1; ++pos) ec_slot[pos] = ws_slot[pos] * inv;
}

template<bool MASKED>
__global__ void k_ew_src(const int* __restrict__ adj_src, const unsigned* __restrict__ indptr_src,
                         const int* __restrict__ orig, const float* __restrict__ w,
                         const float* __restrict__ deg, const float* __restrict__ aggrw, int n,
                         float* __restrict__ ec_slot) {
  int j = blockIdx.x * blockDim.x + threadIdx.x;
  if (j >= n) return;
  int o = orig ? orig[j] : j;
  unsigned s0 = indptr_src[o], s1 = indptr_src[o + 1];
  float d = deg ? deg[j] : (float)(s1 - s0);
  float wn = (w ? w[j] : 1.0f) / (d > 0.f ? d : 1.0f);
  for (unsigned pos = s0; pos < s1; ++pos) {
    int a = adj_src[pos];
    ec_slot[pos] = (!MASKED || a >= 0) ? (wn / aggrw[a]) : 0.f;
  }
}

// ---------------- pooling: multi-block radix select (R3/R8-proven form) ----------------
__global__ void k_hist(const unsigned* __restrict__ keys, int n, const unsigned* __restrict__ state,
                       unsigned* __restrict__ bins, int byte) {
  __shared__ unsigned lb[256];
  for (int i = threadIdx.x; i < 256; i += blockDim.x) lb[i] = 0u;
  __syncthreads();
  unsigned prefix = state[0];
  unsigned mask = (byte == 3) ? 0u : (0xFFFFFFFFu << ((byte + 1) * 8));
  for (int i = blockIdx.x * blockDim.x + threadIdx.x; i < n; i += gridDim.x * blockDim.x) {
    unsigned key = keys[i];
    if ((key & mask) == (prefix & mask))
      atomicAdd(&lb[(key >> (byte * 8)) & 255], 1u);
  }
  __syncthreads();
  for (int i = threadIdx.x; i < 256; i += blockDim.x)
    if (lb[i]) atomicAdd(&bins[i], lb[i]);
}

__global__ void k_pick(unsigned* bins, unsigned* state, int byte) {
  if (threadIdx.x == 0) {
    unsigned r = state[1];
    int b;
    for (b = 255; b > 0; --b) {
      unsigned c = bins[b];
      if (c >= r) break;
      r -= c;
    }
    state[0] |= ((unsigned)b) << (byte * 8);
    state[1] = r;
  }
  __syncthreads();
  for (int i = threadIdx.x; i < 256; i += blockDim.x) bins[i] = 0u;
}

// ---- parallel pack ----
__global__ void k_flags(const unsigned* __restrict__ keys, const unsigned* __restrict__ state,
                        int n, uint2* __restrict__ part) {
  int t = threadIdx.x, lane = t & 63, w = t >> 6;
  int base = blockIdx.x * 1024 + t * 4;
  unsigned T = state[0];
  unsigned cnt = 0;
  #pragma unroll
  for (int j = 0; j < 4; ++j) {
    int i = base + j;
    if (i < n) {
      unsigned key = keys[i];
      cnt += (key > T ? 1u : 0u) + ((key == T ? 1u : 0u) << 16);
    }
  }
  #pragma unroll
  for (int off = 32; off >= 1; off >>= 1) cnt += __shfl_xor(cnt, off);
  __shared__ unsigned ws[4];
  if (lane == 0) ws[w] = cnt;
  __syncthreads();
  if (t == 0) {
    unsigned s = ws[0] + ws[1] + ws[2] + ws[3];
    part[blockIdx.x] = make_uint2(s & 0xffffu, s >> 16);
  }
}

__global__ void k_pack2(const unsigned* __restrict__ keys, const unsigned* __restrict__ state,
                        const uint2* __restrict__ part, const float* __restrict__ aggrw,
                        const int* __restrict__ orig, int n,
                        int* __restrict__ perm, int* __restrict__ new_id,
                        float* __restrict__ w_next, int* __restrict__ orig_next) {
  int t = threadIdx.x, lane = t & 63, w = t >> 6;
  int base = blockIdx.x * 1024 + t * 4;
  unsigned T = state[0], r = state[1];
  unsigned co = 0;
  if (lane < (int)blockIdx.x) {
    uint2 pp = part[lane];
    co = pp.x | (pp.y << 16);
  }
  #pragma unroll
  for (int off = 32; off >= 1; off >>= 1) co += __shfl_xor(co, off);
  unsigned f[4];
  unsigned cnt = 0;
  #pragma unroll
  for (int j = 0; j < 4; ++j) {
    int i = base + j;
    unsigned key = (i < n) ? keys[i] : 0u;
    unsigned gt = (i < n && key > T) ? 1u : 0u;
    unsigned eq = (i < n && key == T) ? 1u : 0u;
    f[j] = gt | (eq << 1);
    cnt += gt + (eq << 16);
  }
  unsigned incl = wave_incl_scan(cnt, lane);
  __shared__ unsigned wsum[4], woff[4];
  if (lane == 63) wsum[w] = incl;
  __syncthreads();
  if (t == 0) { unsigned run = 0; for (int j = 0; j < 4; ++j) { woff[j] = run; run += wsum[j]; } }
  __syncthreads();
  unsigned before = woff[w] + incl - cnt;
  unsigned gt_b = (co & 0xffffu) + (before & 0xffffu);
  unsigned eq_b = (co >> 16) + (before >> 16);
  #pragma unroll
  for (int j = 0; j < 4; ++j) {
    int i = base + j;
    if (i >= n) break;
    unsigned gt = f[j] & 1u, eq = (f[j] >> 1) & 1u;
    bool sel = gt || (eq && eq_b < r);
    if (sel) {
      int pos = (int)(gt_b + (eq_b < r ? eq_b : r));
      perm[pos] = i;
      new_id[i] = pos;
      w_next[pos] = aggrw[i];
      orig_next[pos] = orig ? orig[i] : i;
    } else {
      new_id[i] = -1;
    }
    gt_b += gt; eq_b += eq;
  }
}

__global__ void k_gate(const float* __restrict__ xin, const int* __restrict__ perm,
                       const float* __restrict__ score, int k, float* __restrict__ xout,
                       unsigned* __restrict__ outbf) {
  int wid = (blockIdx.x * blockDim.x + threadIdx.x) >> 6;
  int lane = threadIdx.x & 63;
  if (wid >= k) return;
  int j = perm[wid];
  float g = tanhf(score[j]);
  float2 v = *(const float2*)(xin + (size_t)j * D + lane * 2);
  v.x *= g; v.y *= g;
  *(float2*)(xout + (size_t)wid * D + lane * 2) = v;
  if (outbf) {
    unsigned p = (unsigned)f2bf(v.x) | ((unsigned)f2bf(v.y) << 16);
    outbf[(size_t)wid * 64 + lane] = p;
  }
}

// unpool: full pass over n rows; row r = xin[new_id[r]] (bf16) or zeros
__global__ void k_unpool_bf(const float* __restrict__ xin, const int* __restrict__ new_id,
                            int n, unsigned* __restrict__ outbf) {
  int wid = (blockIdx.x * blockDim.x + threadIdx.x) >> 6;
  int lane = threadIdx.x & 63;
  if (wid >= n) return;
  int j = new_id[wid];
  unsigned pk = 0u;
  if (j >= 0) {
    float2 v = *(const float2*)(xin + (size_t)j * D + lane * 2);
    pk = (unsigned)f2bf(v.x) | ((unsigned)f2bf(v.y) << 16);
  }
  outbf[(size_t)wid * 64 + lane] = pk;
}

// =============================================================================
extern "C" void kernel_launch(void* const* d_in, const int* in_sizes, int n_in,
                              void* d_out, int out_size, void* d_ws, size_t ws_size,
                              hipStream_t stream) {
  const float* x_in   = (const float*)d_in[0];
  const int*   ei     = (const int*)d_in[1];
  const int*   src0   = ei;
  const int*   dst0   = ei + E0;
  const float* Wl     = (const float*)d_in[2];
  const float* bl     = (const float*)d_in[3];
  const float* Wr     = (const float*)d_in[4];
  const float* pool_p = (const float*)d_in[5];
  float* out = (float*)d_out;

  const int n0 = N0, k0 = 25000, n1 = 25000, k1 = 12500, n2 = 12500;
  const int NCH0 = (N0 + 1023) / 1024;   // 49

  char* ws = (char*)d_ws;
  size_t off = 0;
  auto alloc = [&](size_t bytes) -> char* {
    char* p = ws + off;
    off += (bytes + 255) & ~(size_t)255;
    return p;
  };
  const size_t NBY = (size_t)N0 * D * 4;
  float* B0    = (float*)alloc(NBY);
  float* B1    = (float*)alloc(NBY);
  float* B2    = (float*)alloc(NBY);
  float* down0 = (float*)alloc(NBY);
  float* down1 = (float*)alloc(NBY / 2);
  unsigned* MA = (unsigned*)alloc((size_t)N0 * D * 2);
  unsigned* MB = (unsigned*)alloc((size_t)N0 * D * 2);
  int* adj0_dst = (int*)alloc(E0 * 4);
  int* adj0_src = (int*)alloc(E0 * 4);
  int* adj1_dst = (int*)alloc(E0 * 4);
  int* adj1_src = (int*)alloc(E0 * 4);
  float* ec0_src = (float*)alloc(E0 * 4);
  float* ec1_src = (float*)alloc(E0 * 4);
  float* ec_dst  = (float*)alloc(E0 * 4);
  float* ws_slot = (float*)alloc(E0 * 4);
  int* adj2_dst  = (int*)ws_slot;          // alias: ws_slot dead before adj2 is built
  unsigned* rank_src = (unsigned*)alloc(E0 * 4);
  unsigned* rank_dst = (unsigned*)alloc(E0 * 4);
  unsigned* indptr_dst = (unsigned*)alloc((N0 + 1) * 4);
  unsigned* indptr_src = (unsigned*)alloc((N0 + 1) * 4);
  unsigned* cnt_src = (unsigned*)alloc(N0 * 4);
  unsigned* cnt_dst = (unsigned*)alloc(N0 * 4);
  float* deg   = (float*)alloc(N0 * 4);
  float* aggrw = (float*)alloc(N0 * 4);
  float* w1 = (float*)alloc(n1 * 4);
  float* w2 = (float*)alloc(n2 * 4);
  float* score = (float*)alloc(N0 * 4);
  unsigned* keys = (unsigned*)alloc(N0 * 4);
  int* perm0 = (int*)alloc(k0 * 4);
  int* perm1 = (int*)alloc(k1 * 4);
  int* orig1 = (int*)alloc(k0 * 4);
  int* orig2 = (int*)alloc(k1 * 4);
  int* new_id0 = (int*)alloc(N0 * 4);
  int* new_id1 = (int*)alloc(N0 * 4);
  unsigned* bins  = (unsigned*)alloc(256 * 4);
  unsigned* state = (unsigned*)alloc(16);
  unsigned* spart = (unsigned*)alloc(128 * 4);   // [2][64]
  uint2* ppart = (uint2*)alloc(64 * 8);
  unsigned short* Bh = (unsigned short*)alloc((size_t)10 * 32768 * 2);
  unsigned short* Bm = (unsigned short*)alloc((size_t)10 * 32768 * 2);
  unsigned short* Bl = (unsigned short*)alloc((size_t)10 * 32768 * 2);

  const int EG = (E0 + 255) / 256;

  // ---- CSR build ----
  hipMemsetAsync(cnt_src, 0, N0 * 4, stream);
  hipMemsetAsync(cnt_dst, 0, N0 * 4, stream);
  k_count<<<EG, 256, 0, stream>>>(src0, dst0, cnt_src, cnt_dst, rank_src, rank_dst);
  k_psum2<<<dim3(NCH0, 2), 256, 0, stream>>>(cnt_src, cnt_dst, N0, spart);
  k_sapply2<<<dim3(NCH0, 2), 256, 0, stream>>>(cnt_src, cnt_dst, spart, N0, NCH0,
                                               indptr_src, indptr_dst);
  k_fill2<<<EG, 256, 0, stream>>>(src0, dst0, rank_src, rank_dst, indptr_src, indptr_dst,
                                  adj0_src, adj0_dst);
  k_wt_pk3<<<(10 * 8 * 8 * 64 + 255) / 256, 256, 0, stream>>>(Wl, Wr, Bh, Bm, Bl);

  auto gemm6 = [&](const float* meanb, const float* xin, float* yout, int n, int cidx) {
    size_t o = (size_t)cidx * 32768;
    k_gemm_mfma6<<<(n + 63) / 64, 256, 0, stream>>>(meanb, xin, Bh + o, Bm + o, Bl + o,
                                                    bl + cidx * 128, yout, n);
  };
  auto gemm_mx = [&](const float* meanb, const float* xin, float* yout, unsigned short* ybf,
                     const float* skip, int n, int cidx) {
    size_t o = (size_t)cidx * 32768;
    k_gemm_mfma<<<(n + 63) / 64, 256, 0, stream>>>(meanb, xin, Bh + o, Bm + o,
                                                   bl + cidx * 128, skip, yout, ybf, n);
  };

  // pool (score/keys + select-state init already produced by the fused econv)
  auto pool_sel = [&](const float* xpool, int n, int kk, const int* orig,
                      int* perm, int* nid, float* w_next, int* orig_next,
                      float* xout, unsigned* xout_bf) {
    int nch = (n + 1023) / 1024;
    for (int byte = 3; byte >= 0; --byte) {
      k_hist<<<256, 256, 0, stream>>>(keys, n, state, bins, byte);
      k_pick<<<1, 256, 0, stream>>>(bins, state, byte);
    }
    k_flags<<<nch, 256, 0, stream>>>(keys, state, n, ppart);
    k_pack2<<<nch, 256, 0, stream>>>(keys, state, ppart, aggrw, orig, n, perm, nid, w_next, orig_next);
    k_gate<<<((kk + 3) / 4), 256, 0, stream>>>(xpool, perm, score, kk, xout, xout_bf);
  };

  const int G0 = (n0 + 3) / 4, G1 = (n1 + 3) / 4, G2 = (n2 + 3) / 4;

  // ======== down level 0 (f32, selection-exact) ========
  k_gf32<true, false, false, false><<<G0, 256, 0, stream>>>(x_in, adj0_dst, nullptr, indptr_dst,
      nullptr, n0, B1, nullptr, nullptr, nullptr, nullptr, nullptr, 0);
  gemm6(B1, x_in, B2, n0, 0);
  k_gf32<true, false, false, false><<<G0, 256, 0, stream>>>(B2, adj0_dst, nullptr, indptr_dst,
      nullptr, n0, B1, nullptr, nullptr, nullptr, nullptr, nullptr, 0);
  gemm6(B1, B2, down0, n0, 1);
  k_ew_dst<false><<<(n0 + 255) / 256, 256, 0, stream>>>(adj0_dst, indptr_dst, indptr_src, nullptr,
                                                        nullptr, nullptr, n0, ws_slot, aggrw, ec_dst);
  k_ew_src<false><<<(n0 + 255) / 256, 256, 0, stream>>>(adj0_src, indptr_src, nullptr, nullptr,
                                                        nullptr, aggrw, n0, ec0_src);
  // econv + fused score/keys + select-state init
  k_gf32<false, false, true, true><<<G0, 256, 0, stream>>>(down0, adj0_dst, ec_dst, indptr_dst,
      nullptr, n0, B1, pool_p, score, keys, bins, state, k0);
  pool_sel(B1, n0, k0, nullptr, perm0, new_id0, w1, orig1, B2, nullptr);
  k_adj_next2<<<EG, 256, 0, stream>>>(adj0_dst, adj0_src, new_id0, adj1_dst, adj1_src);

  // ======== down level 1 (f32) ========
  k_gf32<true, true, false, false><<<G1, 256, 0, stream>>>(B2, adj1_dst, nullptr, indptr_dst,
      orig1, n1, B1, nullptr, nullptr, nullptr, nullptr, nullptr, 0);
  gemm6(B1, B2, B0, n1, 2);
  k_gf32<true, true, false, false><<<G1, 256, 0, stream>>>(B0, adj1_dst, nullptr, indptr_dst,
      orig1, n1, B1, nullptr, nullptr, nullptr, nullptr, nullptr, 0);
  gemm6(B1, B0, down1, n1, 3);
  k_deg_mask<<<(n1 + 255) / 256, 256, 0, stream>>>(adj1_src, indptr_src, orig1, n1, deg);
  k_ew_dst<true><<<(n1 + 255) / 256, 256, 0, stream>>>(adj1_dst, indptr_dst, nullptr, orig1, w1,
                                                       deg, n1, ws_slot, aggrw, ec_dst);
  k_ew_src<true><<<(n1 + 255) / 256, 256, 0, stream>>>(adj1_src, indptr_src, orig1, w1, deg, aggrw,
                                                       n1, ec1_src);
  k_gf32<false, true, true, true><<<G1, 256, 0, stream>>>(down1, adj1_dst, ec_dst, indptr_dst,
      orig1, n1, B1, pool_p + D, score, keys, bins, state, k1);
  pool_sel(B1, n1, k1, orig1, perm1, new_id1, w2, orig2, B2, MA);
  k_adj_next<<<EG, 256, 0, stream>>>(adj1_dst, new_id1, adj2_dst);   // aliases ws_slot (dead)

  // ======== bottom (bf16 gathers, MFMA convs) ========
  k_gbf<true, true, false><<<G2, 256, 0, stream>>>(MA, adj2_dst, nullptr, indptr_dst, orig2, n2, B1, nullptr);
  gemm_mx(B1, B2, B0, (unsigned short*)MB, nullptr, n2, 4);
  k_gbf<true, true, false><<<G2, 256, 0, stream>>>(MB, adj2_dst, nullptr, indptr_dst, orig2, n2, B1, nullptr);
  gemm_mx(B1, B0, B2, nullptr, nullptr, n2, 5);

  // ======== up u=1 (bf16; skip fused into conv 7) ========
  k_unpool_bf<<<G1, 256, 0, stream>>>(B2, new_id1, n1, MA);
  k_gbf<false, true, true><<<G1, 256, 0, stream>>>(MA, adj1_src, ec1_src, indptr_src, orig1, n1, B1, MB);
  k_gbf<true, true, false><<<G1, 256, 0, stream>>>(MB, adj1_dst, nullptr, indptr_dst, orig1, n1, B0, nullptr);
  gemm_mx(B0, B1, B2, (unsigned short*)MA, nullptr, n1, 6);
  k_gbf<true, true, false><<<G1, 256, 0, stream>>>(MA, adj1_dst, nullptr, indptr_dst, orig1, n1, B0, nullptr);
  gemm_mx(B0, B2, B1, nullptr, down1, n1, 7);

  // ======== up u=0 (bf16; skip fused into conv 9) ========
  k_unpool_bf<<<G0, 256, 0, stream>>>(B1, new_id0, n0, MA);
  k_gbf<false, false, true><<<G0, 256, 0, stream>>>(MA, adj0_src, ec0_src, indptr_src, nullptr, n0, B2, MB);
  k_gbf<true, false, false><<<G0, 256, 0, stream>>>(MB, adj0_dst, nullptr, indptr_dst, nullptr, n0, B1, nullptr);
  gemm_mx(B1, B2, B0, (unsigned short*)MA, nullptr, n0, 8);
  k_gbf<true, false, false><<<G0, 256, 0, stream>>>(MA, adj0_dst, nullptr, indptr_dst, nullptr, n0, B1, nullptr);
  gemm_mx(B1, B0, out, nullptr, down0, n0, 9);
}

// Round 11
// 1046.152 us; speedup vs baseline: 1.1405x; 1.0311x over previous
//
#include <hip/hip_runtime.h>
#include <stdint.h>

#define DEV __device__ __forceinline__

constexpr int N0 = 50000;
constexpr int E0 = 800000;
constexpr int D  = 128;

typedef __attribute__((ext_vector_type(8))) short bf16x8;
typedef __attribute__((ext_vector_type(4))) float f32x4;

DEV float bf2f(unsigned u) { return __uint_as_float(u << 16); }
DEV unsigned short f2bf(float f) {
  unsigned u = __float_as_uint(f);
  unsigned r = u + 0x7fffu + ((u >> 16) & 1u);   // round-to-nearest-even
  return (unsigned short)(r >> 16);
}

DEV unsigned wave_incl_scan(unsigned v, int lane) {
  #pragma unroll
  for (int off = 1; off < 64; off <<= 1) {
    unsigned u = __shfl_up(v, (unsigned)off);
    if (lane >= off) v += u;
  }
  return v;
}

DEV unsigned mono_key(float f) {
  unsigned u = __float_as_uint(f);
  return (u & 0x80000000u) ? ~u : (u | 0x80000000u);
}

// ---------------- CSR build ----------------
__global__ void k_count(const int* __restrict__ src, const int* __restrict__ dst,
                        unsigned* cnt_src, unsigned* cnt_dst,
                        unsigned* __restrict__ rank_src, unsigned* __restrict__ rank_dst) {
  int e = blockIdx.x * blockDim.x + threadIdx.x;
  if (e < E0) {
    rank_src[e] = atomicAdd(&cnt_src[src[e]], 1u);
    rank_dst[e] = atomicAdd(&cnt_dst[dst[e]], 1u);
  }
}

// ---- merged 2-array 2-level exclusive scan (y=0: src, y=1: dst) ----
__global__ void k_psum2(const unsigned* __restrict__ in0, const unsigned* __restrict__ in1,
                        int n, unsigned* __restrict__ part) {
  int y = blockIdx.y;
  const unsigned* in = y ? in1 : in0;
  int t = threadIdx.x, lane = t & 63, w = t >> 6;
  int base = blockIdx.x * 1024 + t * 4;
  unsigned s = 0;
  #pragma unroll
  for (int j = 0; j < 4; ++j) { int i = base + j; if (i < n) s += in[i]; }
  #pragma unroll
  for (int off = 32; off >= 1; off >>= 1) s += __shfl_xor(s, off);
  __shared__ unsigned ws[4];
  if (lane == 0) ws[w] = s;
  __syncthreads();
  if (t == 0) part[y * 64 + blockIdx.x] = ws[0] + ws[1] + ws[2] + ws[3];
}

__global__ void k_sapply2(const unsigned* __restrict__ in0, const unsigned* __restrict__ in1,
                          const unsigned* __restrict__ part, int n, int nch,
                          unsigned* __restrict__ out0, unsigned* __restrict__ out1) {
  int y = blockIdx.y;
  const unsigned* in = y ? in1 : in0;
  unsigned* out = y ? out1 : out0;
  int t = threadIdx.x, lane = t & 63, w = t >> 6;
  unsigned c = (lane < (int)blockIdx.x) ? part[y * 64 + lane] : 0u;
  #pragma unroll
  for (int off = 32; off >= 1; off >>= 1) c += __shfl_xor(c, off);
  int base = blockIdx.x * 1024 + t * 4;
  unsigned v[4]; unsigned s = 0;
  #pragma unroll
  for (int j = 0; j < 4; ++j) { int i = base + j; v[j] = (i < n) ? in[i] : 0u; s += v[j]; }
  unsigned incl = wave_incl_scan(s, lane);
  __shared__ unsigned wsum[4], woff[4];
  if (lane == 63) wsum[w] = incl;
  __syncthreads();
  if (t == 0) { unsigned run = 0; for (int j = 0; j < 4; ++j) { woff[j] = run; run += wsum[j]; } }
  __syncthreads();
  unsigned run = c + woff[w] + incl - s;
  #pragma unroll
  for (int j = 0; j < 4; ++j) {
    int i = base + j;
    if (i < n) out[i] = run;
    run += v[j];
  }
  if ((int)blockIdx.x == nch - 1 && t == 0)
    out[n] = c + woff[3] + wsum[3];
}

__global__ void k_fill2(const int* __restrict__ src, const int* __restrict__ dst,
                        const unsigned* __restrict__ rank_src, const unsigned* __restrict__ rank_dst,
                        const unsigned* __restrict__ indptr_src, const unsigned* __restrict__ indptr_dst,
                        int* __restrict__ adj_src, int* __restrict__ adj_dst) {
  int e = blockIdx.x * blockDim.x + threadIdx.x;
  if (e < E0) {
    int s = src[e], d = dst[e];
    adj_dst[indptr_dst[d] + rank_dst[e]] = s;
    adj_src[indptr_src[s] + rank_src[e]] = d;
  }
}

__global__ void k_adj_next2(const int* __restrict__ adjd, const int* __restrict__ adjs,
                            const int* __restrict__ new_id,
                            int* __restrict__ outd, int* __restrict__ outs) {
  int pos = blockIdx.x * blockDim.x + threadIdx.x;
  if (pos < E0) {
    int a = adjd[pos];
    outd[pos] = (a >= 0) ? new_id[a] : -1;
    int b = adjs[pos];
    outs[pos] = (b >= 0) ? new_id[b] : -1;
  }
}

// ---------------- weight prep: 3-plane split-bf16, MFMA fragment order ----------------
__global__ void k_wt_pk3(const float* __restrict__ Wl, const float* __restrict__ Wr,
                         unsigned short* __restrict__ Bh, unsigned short* __restrict__ Bm,
                         unsigned short* __restrict__ Bl) {
  int idx = blockIdx.x * blockDim.x + threadIdx.x;
  if (idx >= 10 * 8 * 8 * 64) return;
  int l  = idx & 63;
  int ct = (idx >> 6) & 7;
  int ks = (idx >> 9) & 7;
  int c  = idx >> 12;          // conv 0..9
  int k0 = ks * 32 + (l >> 4) * 8;
  int o  = ct * 16 + (l & 15);
  const float* Wrow = (k0 < 128) ? (Wl + ((size_t)c * 128 + o) * 128 + k0)
                                 : (Wr + ((size_t)c * 128 + o) * 128 + (k0 - 128));
  size_t base = (size_t)idx * 8;
  #pragma unroll
  for (int j = 0; j < 8; ++j) {
    float wv = Wrow[j];
    unsigned short h = f2bf(wv);
    float r1 = wv - bf2f(h);
    unsigned short m = f2bf(r1);
    float r2 = r1 - bf2f(m);
    Bh[base + j] = h;
    Bm[base + j] = m;
    Bl[base + j] = f2bf(r2);
  }
}

// ---------------- f32 gather: quarter-wave, 4 rows/step x 4-batch; optional fused score ----------------
template<bool MEAN, bool MASKED, bool ECW, bool SCORE>
__global__ void k_gf32(const float* __restrict__ x, const int* __restrict__ adj,
                       const float* __restrict__ ecs, const unsigned* __restrict__ indptr,
                       const int* __restrict__ orig, int n, float* __restrict__ out,
                       const float* __restrict__ p, float* __restrict__ score,
                       unsigned* __restrict__ keys, unsigned* bins, unsigned* state, int kk) {
  if (SCORE && blockIdx.x == 0) {
    int t = threadIdx.x;
    if (t < 256) bins[t] = 0u;
    if (t == 0) { state[0] = 0u; state[1] = (unsigned)kk; }
  }
  int wid = (blockIdx.x * blockDim.x + threadIdx.x) >> 6;
  int lane = threadIdx.x & 63;
  if (wid >= n) return;
  int o = orig ? orig[wid] : wid;
  unsigned s0 = indptr[o], s1 = indptr[o + 1];
  int q = lane >> 4, sl = lane & 15;
  float acc[8];
  #pragma unroll
  for (int k = 0; k < 8; ++k) acc[k] = 0.f;
  float cnt = 0.f;
  for (unsigned idx = s0; idx < s1; idx += 16) {
    #pragma unroll
    for (int j = 0; j < 4; ++j) {
      unsigned e = idx + j * 4 + q;
      if (e < s1) {
        int a = adj[e];
        if (!MASKED || a >= 0) {
          const float4 v0 = *(const float4*)(x + (size_t)a * D + sl * 8);
          const float4 v1 = *(const float4*)(x + (size_t)a * D + sl * 8 + 4);
          if (ECW) {
            float w = ecs[e];
            acc[0] = fmaf(w, v0.x, acc[0]); acc[1] = fmaf(w, v0.y, acc[1]);
            acc[2] = fmaf(w, v0.z, acc[2]); acc[3] = fmaf(w, v0.w, acc[3]);
            acc[4] = fmaf(w, v1.x, acc[4]); acc[5] = fmaf(w, v1.y, acc[5]);
            acc[6] = fmaf(w, v1.z, acc[6]); acc[7] = fmaf(w, v1.w, acc[7]);
          } else {
            acc[0] += v0.x; acc[1] += v0.y; acc[2] += v0.z; acc[3] += v0.w;
            acc[4] += v1.x; acc[5] += v1.y; acc[6] += v1.z; acc[7] += v1.w;
          }
          cnt += 1.f;
        }
      }
    }
  }
  #pragma unroll
  for (int k = 0; k < 8; ++k) {
    acc[k] += __shfl_xor(acc[k], 16);
    acc[k] += __shfl_xor(acc[k], 32);
  }
  if (MEAN) {
    cnt += __shfl_xor(cnt, 16);
    cnt += __shfl_xor(cnt, 32);
    if (!MASKED) cnt = (float)(s1 - s0);
    float inv = 1.0f / fmaxf(cnt, 1.0f);
    #pragma unroll
    for (int k = 0; k < 8; ++k) acc[k] *= inv;
  }
  if (q == 0) {
    *(float4*)(out + (size_t)wid * D + sl * 8)     = make_float4(acc[0], acc[1], acc[2], acc[3]);
    *(float4*)(out + (size_t)wid * D + sl * 8 + 4) = make_float4(acc[4], acc[5], acc[6], acc[7]);
    if (SCORE) {
      float partial = 0.f, pn = 0.f;
      #pragma unroll
      for (int k = 0; k < 8; ++k) {
        float pv = p[sl * 8 + k];
        partial = fmaf(acc[k], pv, partial);
        pn = fmaf(pv, pv, pn);
      }
      #pragma unroll
      for (int off = 8; off >= 1; off >>= 1) {
        partial += __shfl_xor(partial, off);
        pn += __shfl_xor(pn, off);
      }
      if (sl == 0) {
        float sc = partial * (1.0f / sqrtf(pn));
        score[wid] = sc;
        keys[wid] = mono_key(sc);
      }
    }
  }
}

// ---------------- bf16 gather: quarter-wave, 4 rows/step x 4-batch ----------------
template<bool MEAN, bool MASKED, bool ECW>
__global__ void k_gbf(const unsigned* __restrict__ xb, const int* __restrict__ adj,
                      const float* __restrict__ ecs, const unsigned* __restrict__ indptr,
                      const int* __restrict__ orig, int n,
                      float* __restrict__ out, unsigned* __restrict__ outbf) {
  int wid = (blockIdx.x * blockDim.x + threadIdx.x) >> 6;
  int lane = threadIdx.x & 63;
  if (wid >= n) return;
  int o = orig ? orig[wid] : wid;
  unsigned s0 = indptr[o], s1 = indptr[o + 1];
  int q = lane >> 4, sl = lane & 15;
  float acc[8];
  #pragma unroll
  for (int k = 0; k < 8; ++k) acc[k] = 0.f;
  float cnt = 0.f;
  for (unsigned idx = s0; idx < s1; idx += 16) {
    #pragma unroll
    for (int j = 0; j < 4; ++j) {
      unsigned e = idx + j * 4 + q;
      if (e < s1) {
        int a = adj[e];
        if (!MASKED || a >= 0) {
          const uint4 v = *(const uint4*)(xb + (size_t)a * 64 + sl * 4);
          float f0 = bf2f(v.x & 0xffffu), f1 = bf2f(v.x >> 16);
          float f2 = bf2f(v.y & 0xffffu), f3 = bf2f(v.y >> 16);
          float f4 = bf2f(v.z & 0xffffu), f5 = bf2f(v.z >> 16);
          float f6 = bf2f(v.w & 0xffffu), f7 = bf2f(v.w >> 16);
          if (ECW) {
            float w = ecs[e];
            acc[0] = fmaf(w, f0, acc[0]); acc[1] = fmaf(w, f1, acc[1]);
            acc[2] = fmaf(w, f2, acc[2]); acc[3] = fmaf(w, f3, acc[3]);
            acc[4] = fmaf(w, f4, acc[4]); acc[5] = fmaf(w, f5, acc[5]);
            acc[6] = fmaf(w, f6, acc[6]); acc[7] = fmaf(w, f7, acc[7]);
          } else {
            acc[0] += f0; acc[1] += f1; acc[2] += f2; acc[3] += f3;
            acc[4] += f4; acc[5] += f5; acc[6] += f6; acc[7] += f7;
          }
          cnt += 1.f;
        }
      }
    }
  }
  #pragma unroll
  for (int k = 0; k < 8; ++k) {
    acc[k] += __shfl_xor(acc[k], 16);
    acc[k] += __shfl_xor(acc[k], 32);
  }
  if (MEAN) {
    cnt += __shfl_xor(cnt, 16);
    cnt += __shfl_xor(cnt, 32);
    if (!MASKED) cnt = (float)(s1 - s0);
    float inv = 1.0f / fmaxf(cnt, 1.0f);
    #pragma unroll
    for (int k = 0; k < 8; ++k) acc[k] *= inv;
  }
  if (q == 0) {
    *(float4*)(out + (size_t)wid * D + sl * 8)     = make_float4(acc[0], acc[1], acc[2], acc[3]);
    *(float4*)(out + (size_t)wid * D + sl * 8 + 4) = make_float4(acc[4], acc[5], acc[6], acc[7]);
    if (outbf) {
      uint4 p;
      p.x = (unsigned)f2bf(acc[0]) | ((unsigned)f2bf(acc[1]) << 16);
      p.y = (unsigned)f2bf(acc[2]) | ((unsigned)f2bf(acc[3]) << 16);
      p.z = (unsigned)f2bf(acc[4]) | ((unsigned)f2bf(acc[5]) << 16);
      p.w = (unsigned)f2bf(acc[6]) | ((unsigned)f2bf(acc[7]) << 16);
      *(uint4*)(outbf + (size_t)wid * 64 + sl * 4) = p;
    }
  }
}

// ---------------- 6-term 3-way-split MFMA GEMM (convs 0-3, selection-critical) ----------------
__launch_bounds__(256)
__global__ void k_gemm_mfma6(const float* __restrict__ mean, const float* __restrict__ xin,
                             const unsigned short* __restrict__ Bh, const unsigned short* __restrict__ Bm,
                             const unsigned short* __restrict__ Bl,
                             const float* __restrict__ bias,
                             float* __restrict__ y, int n) {
  int tid = threadIdx.x;
  int lane = tid & 63, w = tid >> 6;
  int row0 = blockIdx.x * 64 + w * 16;
  int arow = row0 + (lane & 15);
  int kgrp = lane >> 4;
  bool rowok = arow < n;
  f32x4 acc[8];
  #pragma unroll
  for (int ct = 0; ct < 8; ++ct) acc[ct] = f32x4{0.f, 0.f, 0.f, 0.f};

  #pragma unroll
  for (int ks = 0; ks < 8; ++ks) {
    const float* A = (ks < 4) ? mean : xin;
    int kk = (ks & 3) * 32 + kgrp * 8;
    float av[8];
    if (rowok) {
      float4 x0 = *(const float4*)(A + (size_t)arow * D + kk);
      float4 x1 = *(const float4*)(A + (size_t)arow * D + kk + 4);
      av[0] = x0.x; av[1] = x0.y; av[2] = x0.z; av[3] = x0.w;
      av[4] = x1.x; av[5] = x1.y; av[6] = x1.z; av[7] = x1.w;
    } else {
      #pragma unroll
      for (int j = 0; j < 8; ++j) av[j] = 0.f;
    }
    bf16x8 ah, am, al;
    #pragma unroll
    for (int j = 0; j < 8; ++j) {
      unsigned short h = f2bf(av[j]);
      float r1 = av[j] - bf2f(h);
      unsigned short m = f2bf(r1);
      float r2 = r1 - bf2f(m);
      ah[j] = (short)h; am[j] = (short)m; al[j] = (short)f2bf(r2);
    }
    #pragma unroll
    for (int ct = 0; ct < 8; ++ct) {
      size_t boff = (((size_t)ks * 8 + ct) * 64 + lane) * 8;
      bf16x8 bh = *(const bf16x8*)(Bh + boff);
      bf16x8 bm = *(const bf16x8*)(Bm + boff);
      bf16x8 bl = *(const bf16x8*)(Bl + boff);
      acc[ct] = __builtin_amdgcn_mfma_f32_16x16x32_bf16(ah, bh, acc[ct], 0, 0, 0);
      acc[ct] = __builtin_amdgcn_mfma_f32_16x16x32_bf16(ah, bm, acc[ct], 0, 0, 0);
      acc[ct] = __builtin_amdgcn_mfma_f32_16x16x32_bf16(am, bh, acc[ct], 0, 0, 0);
      acc[ct] = __builtin_amdgcn_mfma_f32_16x16x32_bf16(am, bm, acc[ct], 0, 0, 0);
      acc[ct] = __builtin_amdgcn_mfma_f32_16x16x32_bf16(ah, bl, acc[ct], 0, 0, 0);
      acc[ct] = __builtin_amdgcn_mfma_f32_16x16x32_bf16(al, bh, acc[ct], 0, 0, 0);
    }
  }
  int ccol = lane & 15;
  #pragma unroll
  for (int ct = 0; ct < 8; ++ct) {
    int col = ct * 16 + ccol;
    float bb = bias[col];
    #pragma unroll
    for (int r = 0; r < 4; ++r) {
      int row = row0 + kgrp * 4 + r;
      if (row < n) y[(size_t)row * D + col] = acc[ct][r] + bb;
    }
  }
}

// ---------------- 3-term split-bf16 MFMA GEMM (convs 4-9, post-selection) ----------------
__launch_bounds__(256)
__global__ void k_gemm_mfma(const float* __restrict__ mean, const float* __restrict__ xin,
                            const unsigned short* __restrict__ Bhi, const unsigned short* __restrict__ Blo,
                            const float* __restrict__ bias, const float* __restrict__ skip,
                            float* __restrict__ y, unsigned short* __restrict__ ybf, int n) {
  int tid = threadIdx.x;
  int lane = tid & 63, w = tid >> 6;
  int row0 = blockIdx.x * 64 + w * 16;
  int arow = row0 + (lane & 15);
  int kgrp = lane >> 4;
  bool rowok = arow < n;
  f32x4 acc[8];
  #pragma unroll
  for (int ct = 0; ct < 8; ++ct) acc[ct] = f32x4{0.f, 0.f, 0.f, 0.f};

  #pragma unroll
  for (int ks = 0; ks < 8; ++ks) {
    const float* A = (ks < 4) ? mean : xin;
    int kk = (ks & 3) * 32 + kgrp * 8;
    float av[8];
    if (rowok) {
      float4 x0 = *(const float4*)(A + (size_t)arow * D + kk);
      float4 x1 = *(const float4*)(A + (size_t)arow * D + kk + 4);
      av[0] = x0.x; av[1] = x0.y; av[2] = x0.z; av[3] = x0.w;
      av[4] = x1.x; av[5] = x1.y; av[6] = x1.z; av[7] = x1.w;
    } else {
      #pragma unroll
      for (int j = 0; j < 8; ++j) av[j] = 0.f;
    }
    bf16x8 ahi, alo;
    #pragma unroll
    for (int j = 0; j < 8; ++j) {
      unsigned short h = f2bf(av[j]);
      ahi[j] = (short)h;
      alo[j] = (short)f2bf(av[j] - bf2f(h));
    }
    #pragma unroll
    for (int ct = 0; ct < 8; ++ct) {
      size_t boff = (((size_t)ks * 8 + ct) * 64 + lane) * 8;
      bf16x8 bh = *(const bf16x8*)(Bhi + boff);
      bf16x8 bl = *(const bf16x8*)(Blo + boff);
      acc[ct] = __builtin_amdgcn_mfma_f32_16x16x32_bf16(ahi, bh, acc[ct], 0, 0, 0);
      acc[ct] = __builtin_amdgcn_mfma_f32_16x16x32_bf16(alo, bh, acc[ct], 0, 0, 0);
      acc[ct] = __builtin_amdgcn_mfma_f32_16x16x32_bf16(ahi, bl, acc[ct], 0, 0, 0);
    }
  }
  int ccol = lane & 15;
  #pragma unroll
  for (int ct = 0; ct < 8; ++ct) {
    int col = ct * 16 + ccol;
    float bb = bias[col];
    #pragma unroll
    for (int r = 0; r < 4; ++r) {
      int row = row0 + kgrp * 4 + r;
      if (row < n) {
        float v = acc[ct][r] + bb;
        if (skip) v += skip[(size_t)row * D + col];
        y[(size_t)row * D + col] = v;
        if (ybf) ybf[(size_t)row * D + col] = f2bf(v);
      }
    }
  }
}

// ---------------- cal_ew ----------------
__global__ void k_deg_mask(const int* __restrict__ adj_src, const unsigned* __restrict__ indptr_src,
                           const int* __restrict__ orig, int n, float* __restrict__ deg) {
  int j = blockIdx.x * blockDim.x + threadIdx.x;
  if (j >= n) return;
  int o = orig ? orig[j] : j;
  unsigned s0 = indptr_src[o], s1 = indptr_src[o + 1];
  float d = 0.f;
  for (unsigned i = s0; i < s1; ++i) d += (adj_src[i] >= 0) ? 1.f : 0.f;
  deg[j] = d;
}

template<bool MASKED>
__global__ void k_ew_dst(const int* __restrict__ adj, const unsigned* __restrict__ indptr,
                         const unsigned* __restrict__ ips,
                         const int* __restrict__ orig, const float* __restrict__ w,
                         const float* __restrict__ deg, int n,
                         float* __restrict__ ws_slot, float* __restrict__ aggrw,
                         float* __restrict__ ec_slot) {
  int j = blockIdx.x * blockDim.x + threadIdx.x;
  if (j >= n) return;
  int o = orig ? orig[j] : j;
  unsigned s0 = indptr[o], s1 = indptr[o + 1];
  float s = 1e-12f;
  for (unsigned pos = s0; pos < s1; ++pos) {
    int a = adj[pos];
    float ws = 0.f;
    if (!MASKED || a >= 0) {
      float d = deg ? deg[a] : (float)(ips[a + 1] - ips[a]);
      ws = (w ? w[a] : 1.0f) / (d > 0.f ? d : 1.0f);
    }
    ws_slot[pos] = ws;
    s += ws;
  }
  aggrw[j] = s;
  float inv = 1.0f / s;
  for (unsigned pos = s0; pos < s1; ++pos) ec_slot[pos] = ws_slot[pos] * inv;
}

template<bool MASKED>
__global__ void k_ew_src(const int* __restrict__ adj_src, const unsigned* __restrict__ indptr_src,
                         const int* __restrict__ orig, const float* __restrict__ w,
                         const float* __restrict__ deg, const float* __restrict__ aggrw, int n,
                         float* __restrict__ ec_slot) {
  int j = blockIdx.x * blockDim.x + threadIdx.x;
  if (j >= n) return;
  int o = orig ? orig[j] : j;
  unsigned s0 = indptr_src[o], s1 = indptr_src[o + 1];
  float d = deg ? deg[j] : (float)(s1 - s0);
  float wn = (w ? w[j] : 1.0f) / (d > 0.f ? d : 1.0f);
  for (unsigned pos = s0; pos < s1; ++pos) {
    int a = adj_src[pos];
    ec_slot[pos] = (!MASKED || a >= 0) ? (wn / aggrw[a]) : 0.f;
  }
}

// ---------------- pooling: multi-block radix select ----------------
__global__ void k_hist(const unsigned* __restrict__ keys, int n, const unsigned* __restrict__ state,
                       unsigned* __restrict__ bins, int byte) {
  __shared__ unsigned lb[256];
  for (int i = threadIdx.x; i < 256; i += blockDim.x) lb[i] = 0u;
  __syncthreads();
  unsigned prefix = state[0];
  unsigned mask = (byte == 3) ? 0u : (0xFFFFFFFFu << ((byte + 1) * 8));
  for (int i = blockIdx.x * blockDim.x + threadIdx.x; i < n; i += gridDim.x * blockDim.x) {
    unsigned key = keys[i];
    if ((key & mask) == (prefix & mask))
      atomicAdd(&lb[(key >> (byte * 8)) & 255], 1u);
  }
  __syncthreads();
  for (int i = threadIdx.x; i < 256; i += blockDim.x)
    if (lb[i]) atomicAdd(&bins[i], lb[i]);
}

__global__ void k_pick(unsigned* bins, unsigned* state, int byte) {
  if (threadIdx.x == 0) {
    unsigned r = state[1];
    int b;
    for (b = 255; b > 0; --b) {
      unsigned c = bins[b];
      if (c >= r) break;
      r -= c;
    }
    state[0] |= ((unsigned)b) << (byte * 8);
    state[1] = r;
  }
  __syncthreads();
  for (int i = threadIdx.x; i < 256; i += blockDim.x) bins[i] = 0u;
}

// ---- parallel pack ----
__global__ void k_flags(const unsigned* __restrict__ keys, const unsigned* __restrict__ state,
                        int n, uint2* __restrict__ part) {
  int t = threadIdx.x, lane = t & 63, w = t >> 6;
  int base = blockIdx.x * 1024 + t * 4;
  unsigned T = state[0];
  unsigned cnt = 0;
  #pragma unroll
  for (int j = 0; j < 4; ++j) {
    int i = base + j;
    if (i < n) {
      unsigned key = keys[i];
      cnt += (key > T ? 1u : 0u) + ((key == T ? 1u : 0u) << 16);
    }
  }
  #pragma unroll
  for (int off = 32; off >= 1; off >>= 1) cnt += __shfl_xor(cnt, off);
  __shared__ unsigned ws[4];
  if (lane == 0) ws[w] = cnt;
  __syncthreads();
  if (t == 0) {
    unsigned s = ws[0] + ws[1] + ws[2] + ws[3];
    part[blockIdx.x] = make_uint2(s & 0xffffu, s >> 16);
  }
}

__global__ void k_pack2(const unsigned* __restrict__ keys, const unsigned* __restrict__ state,
                        const uint2* __restrict__ part, const float* __restrict__ aggrw,
                        const int* __restrict__ orig, int n,
                        int* __restrict__ perm, int* __restrict__ new_id,
                        float* __restrict__ w_next, int* __restrict__ orig_next) {
  int t = threadIdx.x, lane = t & 63, w = t >> 6;
  int base = blockIdx.x * 1024 + t * 4;
  unsigned T = state[0], r = state[1];
  unsigned co = 0;
  if (lane < (int)blockIdx.x) {
    uint2 pp = part[lane];
    co = pp.x | (pp.y << 16);
  }
  #pragma unroll
  for (int off = 32; off >= 1; off >>= 1) co += __shfl_xor(co, off);
  unsigned f[4];
  unsigned cnt = 0;
  #pragma unroll
  for (int j = 0; j < 4; ++j) {
    int i = base + j;
    unsigned key = (i < n) ? keys[i] : 0u;
    unsigned gt = (i < n && key > T) ? 1u : 0u;
    unsigned eq = (i < n && key == T) ? 1u : 0u;
    f[j] = gt | (eq << 1);
    cnt += gt + (eq << 16);
  }
  unsigned incl = wave_incl_scan(cnt, lane);
  __shared__ unsigned wsum[4], woff[4];
  if (lane == 63) wsum[w] = incl;
  __syncthreads();
  if (t == 0) { unsigned run = 0; for (int j = 0; j < 4; ++j) { woff[j] = run; run += wsum[j]; } }
  __syncthreads();
  unsigned before = woff[w] + incl - cnt;
  unsigned gt_b = (co & 0xffffu) + (before & 0xffffu);
  unsigned eq_b = (co >> 16) + (before >> 16);
  #pragma unroll
  for (int j = 0; j < 4; ++j) {
    int i = base + j;
    if (i >= n) break;
    unsigned gt = f[j] & 1u, eq = (f[j] >> 1) & 1u;
    bool sel = gt || (eq && eq_b < r);
    if (sel) {
      int pos = (int)(gt_b + (eq_b < r ? eq_b : r));
      perm[pos] = i;
      new_id[i] = pos;
      w_next[pos] = aggrw[i];
      orig_next[pos] = orig ? orig[i] : i;
    } else {
      new_id[i] = -1;
    }
    gt_b += gt; eq_b += eq;
  }
}

__global__ void k_gate(const float* __restrict__ xin, const int* __restrict__ perm,
                       const float* __restrict__ score, int k, float* __restrict__ xout,
                       unsigned* __restrict__ outbf) {
  int wid = (blockIdx.x * blockDim.x + threadIdx.x) >> 6;
  int lane = threadIdx.x & 63;
  if (wid >= k) return;
  int j = perm[wid];
  float g = tanhf(score[j]);
  float2 v = *(const float2*)(xin + (size_t)j * D + lane * 2);
  v.x *= g; v.y *= g;
  *(float2*)(xout + (size_t)wid * D + lane * 2) = v;
  if (outbf) {
    unsigned p = (unsigned)f2bf(v.x) | ((unsigned)f2bf(v.y) << 16);
    outbf[(size_t)wid * 64 + lane] = p;
  }
}

// =============================================================================
extern "C" void kernel_launch(void* const* d_in, const int* in_sizes, int n_in,
                              void* d_out, int out_size, void* d_ws, size_t ws_size,
                              hipStream_t stream) {
  const float* x_in   = (const float*)d_in[0];
  const int*   ei     = (const int*)d_in[1];
  const int*   src0   = ei;
  const int*   dst0   = ei + E0;
  const float* Wl     = (const float*)d_in[2];
  const float* bl     = (const float*)d_in[3];
  const float* Wr     = (const float*)d_in[4];
  const float* pool_p = (const float*)d_in[5];
  float* out = (float*)d_out;

  const int n0 = N0, k0 = 25000, n1 = 25000, k1 = 12500, n2 = 12500;
  const int NCH0 = (N0 + 1023) / 1024;   // 49

  char* ws = (char*)d_ws;
  size_t off = 0;
  auto alloc = [&](size_t bytes) -> char* {
    char* p = ws + off;
    off += (bytes + 255) & ~(size_t)255;
    return p;
  };
  const size_t NBY = (size_t)N0 * D * 4;
  float* B0    = (float*)alloc(NBY);
  float* B1    = (float*)alloc(NBY);
  float* B2    = (float*)alloc(NBY);
  float* down0 = (float*)alloc(NBY);
  float* down1 = (float*)alloc(NBY / 2);
  unsigned* MA = (unsigned*)alloc((size_t)N0 * D * 2);
  unsigned* MB = (unsigned*)alloc((size_t)N0 * D * 2);
  int* adj0_dst = (int*)alloc(E0 * 4);
  int* adj0_src = (int*)alloc(E0 * 4);
  int* adj1_dst = (int*)alloc(E0 * 4);
  int* adj1_src = (int*)alloc(E0 * 4);
  int* adj2_src = (int*)alloc(E0 * 4);
  float* ec0_src = (float*)alloc(E0 * 4);
  float* ec1_src = (float*)alloc(E0 * 4);
  float* ec_dst  = (float*)alloc(E0 * 4);
  float* ws_slot = (float*)alloc(E0 * 4);
  int* adj2_dst  = (int*)ws_slot;          // alias: ws_slot dead before adj2 is built
  unsigned* rank_src = (unsigned*)alloc(E0 * 4);
  unsigned* rank_dst = (unsigned*)alloc(E0 * 4);
  unsigned* indptr_dst = (unsigned*)alloc((N0 + 1) * 4);
  unsigned* indptr_src = (unsigned*)alloc((N0 + 1) * 4);
  unsigned* cnt_src = (unsigned*)alloc(N0 * 4);
  unsigned* cnt_dst = (unsigned*)alloc(N0 * 4);
  float* deg   = (float*)alloc(N0 * 4);
  float* aggrw = (float*)alloc(N0 * 4);
  float* w1 = (float*)alloc(n1 * 4);
  float* w2 = (float*)alloc(n2 * 4);
  float* score = (float*)alloc(N0 * 4);
  unsigned* keys = (unsigned*)alloc(N0 * 4);
  int* perm0 = (int*)alloc(k0 * 4);
  int* perm1 = (int*)alloc(k1 * 4);
  int* orig1 = (int*)alloc(k0 * 4);
  int* orig2 = (int*)alloc(k1 * 4);
  int* new_id0 = (int*)alloc(N0 * 4);
  int* new_id1 = (int*)alloc(N0 * 4);
  unsigned* bins  = (unsigned*)alloc(256 * 4);
  unsigned* state = (unsigned*)alloc(16);
  unsigned* spart = (unsigned*)alloc(128 * 4);   // [2][64]
  uint2* ppart = (uint2*)alloc(64 * 8);
  unsigned short* Bh = (unsigned short*)alloc((size_t)10 * 32768 * 2);
  unsigned short* Bm = (unsigned short*)alloc((size_t)10 * 32768 * 2);
  unsigned short* Bl = (unsigned short*)alloc((size_t)10 * 32768 * 2);

  const int EG = (E0 + 255) / 256;

  // ---- CSR build ----
  hipMemsetAsync(cnt_src, 0, N0 * 4, stream);
  hipMemsetAsync(cnt_dst, 0, N0 * 4, stream);
  k_count<<<EG, 256, 0, stream>>>(src0, dst0, cnt_src, cnt_dst, rank_src, rank_dst);
  k_psum2<<<dim3(NCH0, 2), 256, 0, stream>>>(cnt_src, cnt_dst, N0, spart);
  k_sapply2<<<dim3(NCH0, 2), 256, 0, stream>>>(cnt_src, cnt_dst, spart, N0, NCH0,
                                               indptr_src, indptr_dst);
  k_fill2<<<EG, 256, 0, stream>>>(src0, dst0, rank_src, rank_dst, indptr_src, indptr_dst,
                                  adj0_src, adj0_dst);
  k_wt_pk3<<<(10 * 8 * 8 * 64 + 255) / 256, 256, 0, stream>>>(Wl, Wr, Bh, Bm, Bl);

  auto gemm6 = [&](const float* meanb, const float* xin, float* yout, int n, int cidx) {
    size_t o = (size_t)cidx * 32768;
    k_gemm_mfma6<<<(n + 63) / 64, 256, 0, stream>>>(meanb, xin, Bh + o, Bm + o, Bl + o,
                                                    bl + cidx * 128, yout, n);
  };
  auto gemm_mx = [&](const float* meanb, const float* xin, float* yout, unsigned short* ybf,
                     const float* skip, int n, int cidx) {
    size_t o = (size_t)cidx * 32768;
    k_gemm_mfma<<<(n + 63) / 64, 256, 0, stream>>>(meanb, xin, Bh + o, Bm + o,
                                                   bl + cidx * 128, skip, yout, ybf, n);
  };

  // pool (score/keys + select-state init already produced by the fused econv)
  auto pool_sel = [&](const float* xpool, int n, int kk, const int* orig,
                      int* perm, int* nid, float* w_next, int* orig_next,
                      float* xout, unsigned* xout_bf) {
    int nch = (n + 1023) / 1024;
    for (int byte = 3; byte >= 0; --byte) {
      k_hist<<<256, 256, 0, stream>>>(keys, n, state, bins, byte);
      k_pick<<<1, 256, 0, stream>>>(bins, state, byte);
    }
    k_flags<<<nch, 256, 0, stream>>>(keys, state, n, ppart);
    k_pack2<<<nch, 256, 0, stream>>>(keys, state, ppart, aggrw, orig, n, perm, nid, w_next, orig_next);
    k_gate<<<((kk + 3) / 4), 256, 0, stream>>>(xpool, perm, score, kk, xout, xout_bf);
  };

  const int G0 = (n0 + 3) / 4, G1 = (n1 + 3) / 4, G2 = (n2 + 3) / 4;

  // ======== down level 0 (f32, selection-exact) ========
  k_gf32<true, false, false, false><<<G0, 256, 0, stream>>>(x_in, adj0_dst, nullptr, indptr_dst,
      nullptr, n0, B1, nullptr, nullptr, nullptr, nullptr, nullptr, 0);
  gemm6(B1, x_in, B2, n0, 0);
  k_gf32<true, false, false, false><<<G0, 256, 0, stream>>>(B2, adj0_dst, nullptr, indptr_dst,
      nullptr, n0, B1, nullptr, nullptr, nullptr, nullptr, nullptr, 0);
  gemm6(B1, B2, down0, n0, 1);
  k_ew_dst<false><<<(n0 + 255) / 256, 256, 0, stream>>>(adj0_dst, indptr_dst, indptr_src, nullptr,
                                                        nullptr, nullptr, n0, ws_slot, aggrw, ec_dst);
  k_ew_src<false><<<(n0 + 255) / 256, 256, 0, stream>>>(adj0_src, indptr_src, nullptr, nullptr,
                                                        nullptr, aggrw, n0, ec0_src);
  // econv + fused score/keys + select-state init
  k_gf32<false, false, true, true><<<G0, 256, 0, stream>>>(down0, adj0_dst, ec_dst, indptr_dst,
      nullptr, n0, B1, pool_p, score, keys, bins, state, k0);
  pool_sel(B1, n0, k0, nullptr, perm0, new_id0, w1, orig1, B2, nullptr);
  k_adj_next2<<<EG, 256, 0, stream>>>(adj0_dst, adj0_src, new_id0, adj1_dst, adj1_src);

  // ======== down level 1 (f32) ========
  k_gf32<true, true, false, false><<<G1, 256, 0, stream>>>(B2, adj1_dst, nullptr, indptr_dst,
      orig1, n1, B1, nullptr, nullptr, nullptr, nullptr, nullptr, 0);
  gemm6(B1, B2, B0, n1, 2);
  k_gf32<true, true, false, false><<<G1, 256, 0, stream>>>(B0, adj1_dst, nullptr, indptr_dst,
      orig1, n1, B1, nullptr, nullptr, nullptr, nullptr, nullptr, 0);
  gemm6(B1, B0, down1, n1, 3);
  k_deg_mask<<<(n1 + 255) / 256, 256, 0, stream>>>(adj1_src, indptr_src, orig1, n1, deg);
  k_ew_dst<true><<<(n1 + 255) / 256, 256, 0, stream>>>(adj1_dst, indptr_dst, nullptr, orig1, w1,
                                                       deg, n1, ws_slot, aggrw, ec_dst);
  k_ew_src<true><<<(n1 + 255) / 256, 256, 0, stream>>>(adj1_src, indptr_src, orig1, w1, deg, aggrw,
                                                       n1, ec1_src);
  k_gf32<false, true, true, true><<<G1, 256, 0, stream>>>(down1, adj1_dst, ec_dst, indptr_dst,
      orig1, n1, B1, pool_p + D, score, keys, bins, state, k1);
  pool_sel(B1, n1, k1, orig1, perm1, new_id1, w2, orig2, B2, MA);
  k_adj_next2<<<EG, 256, 0, stream>>>(adj1_dst, adj1_src, new_id1, adj2_dst, adj2_src);

  // ======== bottom (bf16 gathers, MFMA convs; conv5 emits compact n2 mirror) ========
  k_gbf<true, true, false><<<G2, 256, 0, stream>>>(MA, adj2_dst, nullptr, indptr_dst, orig2, n2, B1, nullptr);
  gemm_mx(B1, B2, B0, (unsigned short*)MB, nullptr, n2, 4);
  k_gbf<true, true, false><<<G2, 256, 0, stream>>>(MB, adj2_dst, nullptr, indptr_dst, orig2, n2, B1, nullptr);
  gemm_mx(B1, B0, B2, (unsigned short*)MA, nullptr, n2, 5);

  // ======== up u=1 (direct-compact econv via adj2_src; skip fused into conv 7) ========
  k_gbf<false, true, true><<<G1, 256, 0, stream>>>(MA, adj2_src, ec1_src, indptr_src, orig1, n1, B1, MB);
  k_gbf<true, true, false><<<G1, 256, 0, stream>>>(MB, adj1_dst, nullptr, indptr_dst, orig1, n1, B0, nullptr);
  gemm_mx(B0, B1, B2, (unsigned short*)MA, nullptr, n1, 6);
  k_gbf<true, true, false><<<G1, 256, 0, stream>>>(MA, adj1_dst, nullptr, indptr_dst, orig1, n1, B0, nullptr);
  gemm_mx(B0, B2, B1, (unsigned short*)MA, down1, n1, 7);   // compact n1 mirror for up0

  // ======== up u=0 (direct-compact econv via adj1_src; skip fused into conv 9) ========
  k_gbf<false, true, true><<<G0, 256, 0, stream>>>(MA, adj1_src, ec0_src, indptr_src, nullptr, n0, B2, MB);
  k_gbf<true, false, false><<<G0, 256, 0, stream>>>(MB, adj0_dst, nullptr, indptr_dst, nullptr, n0, B1, nullptr);
  gemm_mx(B1, B2, B0, (unsigned short*)MA, nullptr, n0, 8);
  k_gbf<true, false, false><<<G0, 256, 0, stream>>>(MA, adj0_dst, nullptr, indptr_dst, nullptr, n0, B1, nullptr);
  gemm_mx(B1, B0, out, nullptr, down0, n0, 9);
}